// Round 9
// baseline (416.460 us; speedup 1.0000x reference)
//
#include <hip/hip_runtime.h>
#include <hip/hip_bf16.h>
#include <math.h>

// ---------------- problem constants ----------------
constexpr int NN  = 32768;   // nodes
constexpr int BG  = 64;      // graphs
constexpr int NPG = 512;     // nodes per graph
constexpr int EG  = 524288;  // edges
constexpr int HH  = 4;       // heads
constexpr int FH  = 64;      // per-head dim
constexpr int CC  = 256;     // H*Fh
constexpr int FIN = 128;
constexpr int KP1 = 256;     // pool1 k
constexpr int KP2 = 128;     // pool2 k
constexpr int NS  = 4;       // register edge slots: fast path deg <= 64

typedef __attribute__((ext_vector_type(8))) short short8;  // 8 bf16 = 4 VGPRs
typedef __attribute__((ext_vector_type(4))) float f32x4;

__device__ inline float leaky02(float v) { return v > 0.0f ? v : 0.2f * v; }

__device__ inline unsigned short f2bf(float v) {
    __hip_bfloat16 h = __float2bfloat16(v);
    return *(unsigned short*)&h;
}
__device__ inline float bf2f(unsigned short u) {
    __hip_bfloat16 h;
    *(unsigned short*)&h = u;
    return __bfloat162float(h);
}
__device__ inline void split2(float v, unsigned short& hi, unsigned short& lo) {
    hi = f2bf(v);
    lo = f2bf(v - bf2f(hi));
}

// ---------------- split-precision conversion kernels ----------------------
// x fp32 -> (hi,lo) bf16, vectorized 4 elems/thread
__global__ __launch_bounds__(256) void conv_split(const float* __restrict__ X,
                                                  unsigned short* __restrict__ Hi,
                                                  unsigned short* __restrict__ Lo,
                                                  int n4) {
    int i = blockIdx.x * 256 + threadIdx.x;
    if (i >= n4) return;
    float4 v = ((const float4*)X)[i];
    ushort4 h, l;
    split2(v.x, h.x, l.x);
    split2(v.y, h.y, l.y);
    split2(v.z, h.z, l.z);
    split2(v.w, h.w, l.w);
    ((ushort4*)Hi)[i] = h;
    ((ushort4*)Lo)[i] = l;
}

// W1 [128x256], W2 [256x256] fp32 -> transposed split Bt[n][k] bf16
__global__ __launch_bounds__(256) void conv_wT(const float* __restrict__ W1,
                                               const float* __restrict__ W2,
                                               unsigned short* __restrict__ w1th,
                                               unsigned short* __restrict__ w1tl,
                                               unsigned short* __restrict__ w2th,
                                               unsigned short* __restrict__ w2tl) {
    int idx = blockIdx.x * 256 + threadIdx.x;      // 0 .. 98303
    if (idx < 256 * FIN) {
        int n = idx >> 7, k = idx & 127;           // Bt index = n*128+k
        unsigned short h, l;
        split2(W1[k * CC + n], h, l);
        w1th[idx] = h; w1tl[idx] = l;
    } else {
        int j = idx - 256 * FIN;                   // 0 .. 65535
        int n = j >> 8, k = j & 255;
        unsigned short h, l;
        split2(W2[k * CC + n], h, l);
        w2th[j] = h; w2tl[j] = l;
    }
}

// ---------------- MFMA GEMM: C[M,256] = A[M,K]@B[K,256], split-bf16 -------
// One block = 16 rows x 256 cols, 4 waves; wave w owns cols w*64..+63 (head w).
// No LDS, no barriers. A row-major bf16 [M][K]; B transposed bf16 [256][K].
// acc = Ahi*Bhi + Ahi*Blo + Alo*Bhi  (fp32 AGPR accum, ~2^-16 rel error).
// Fragment layouts (m89-verified): A/B operand lane l -> idx=l&15, k=(l>>4)*8+j;
// C/D lane l -> col=l&15, row=(l>>4)*4+reg.
// Epilogue: es/ed per-head attention dots (wave w = head w), 16-lane shfl.
__global__ __launch_bounds__(256, 4) void gemm_mfma_attn(
        const unsigned short* __restrict__ Ahi, const unsigned short* __restrict__ Alo,
        const unsigned short* __restrict__ Bth, const unsigned short* __restrict__ Btl,
        float* __restrict__ Cm, int K,
        const float* __restrict__ a_src, const float* __restrict__ a_dst,
        float* __restrict__ es, float* __restrict__ ed) {
    const int t = threadIdx.x;
    const int w = t >> 6;          // wave = col strip = head
    const int l = t & 63;
    // XCD swizzle: graph g -> XCD g&7 (matches gat_edge consumer)
    const int bx   = blockIdx.x;               // 0..2047
    const int xcd  = bx & 7;
    const int slot = bx >> 3;                  // 0..255
    const int gph  = xcd + ((slot >> 5) << 3); // graph
    const int row0 = gph * NPG + ((slot & 31) << 4);
    const int m = l & 15;
    const int q = l >> 4;
    const int ncol0 = w * 64;

    const unsigned short* aHp = Ahi + (size_t)(row0 + m) * K + q * 8;
    const unsigned short* aLp = Alo + (size_t)(row0 + m) * K + q * 8;

    f32x4 acc[4];
#pragma unroll
    for (int c = 0; c < 4; ++c) acc[c] = (f32x4){0.f, 0.f, 0.f, 0.f};

    for (int k0 = 0; k0 < K; k0 += 32) {
        short8 ah = *(const short8*)(aHp + k0);
        short8 al = *(const short8*)(aLp + k0);
#pragma unroll
        for (int c = 0; c < 4; ++c) {
            const size_t boff = (size_t)(ncol0 + c * 16 + m) * K + k0 + q * 8;
            short8 bh = *(const short8*)(Bth + boff);
            short8 bl = *(const short8*)(Btl + boff);
            acc[c] = __builtin_amdgcn_mfma_f32_16x16x32_bf16(ah, bh, acc[c], 0, 0, 0);
            acc[c] = __builtin_amdgcn_mfma_f32_16x16x32_bf16(ah, bl, acc[c], 0, 0, 0);
            acc[c] = __builtin_amdgcn_mfma_f32_16x16x32_bf16(al, bh, acc[c], 0, 0, 0);
        }
    }

    // ---- C store: lane l holds rows q*4+r, col = c*16 + (l&15) ----
#pragma unroll
    for (int c = 0; c < 4; ++c)
#pragma unroll
        for (int r = 0; r < 4; ++r)
            Cm[(size_t)(row0 + q * 4 + r) * CC + ncol0 + c * 16 + m] = acc[c][r];

    // ---- es/ed epilogue: head w, rows q*4+r ----
    float asv[4], adv[4];
#pragma unroll
    for (int c = 0; c < 4; ++c) {
        asv[c] = a_src[ncol0 + c * 16 + m];
        adv[c] = a_dst[ncol0 + c * 16 + m];
    }
#pragma unroll
    for (int r = 0; r < 4; ++r) {
        float ps = 0.f, pd = 0.f;
#pragma unroll
        for (int c = 0; c < 4; ++c) {
            ps = fmaf(acc[c][r], asv[c], ps);
            pd = fmaf(acc[c][r], adv[c], pd);
        }
#pragma unroll
        for (int o = 8; o >= 1; o >>= 1) {
            ps += __shfl_down(ps, o, 16);
            pd += __shfl_down(pd, o, 16);
        }
        if (m == 0) {
            es[(row0 + q * 4 + r) * HH + w] = ps;
            ed[(row0 + q * 4 + r) * HH + w] = pd;
        }
    }
}

// ---------------- prep: zero cnt + w12 + T = tw2@c1w + bc2 = tb2@c1w -------
__global__ __launch_bounds__(256) void prep(int* __restrict__ cnt,
                                            const float* __restrict__ tw1,
                                            const float* __restrict__ sw2,
                                            const float* __restrict__ tb1,
                                            const float* __restrict__ sb2,
                                            float* __restrict__ w12,
                                            float* __restrict__ b12,
                                            const float* __restrict__ tw2,
                                            const float* __restrict__ c1w,
                                            const float* __restrict__ tb2,
                                            float* __restrict__ T,
                                            float* __restrict__ bc2) {
    const int b = blockIdx.x;
    const int t = threadIdx.x;
    if (b < 128) {
        cnt[b * 256 + t] = 0;
    } else if (b == 128) {
        float s = 0.0f;
        for (int o = 0; o < CC; ++o) s += tw1[t * CC + o] * sw2[o];
        w12[t] = s;
        if (t == 0) {
            float bb = 0.0f;
            for (int o = 0; o < CC; ++o) bb += tb1[o] * sw2[o];
            *b12 = bb + sb2[0];
        }
    } else if (b < 193) {
        const int r = (b - 129) * 4 + (t >> 6);
        const int cth = t & 63;
        float s = 0.0f;
        for (int j = 0; j < CC; ++j) s = fmaf(tw2[r * CC + j], c1w[j * 64 + cth], s);
        T[r * 64 + cth] = s;
    } else if (t < 64) {
        float s = 0.0f;
        for (int j = 0; j < CC; ++j) s = fmaf(tb2[j], c1w[j * 64 + t], s);
        bc2[t] = s;
    }
}

// ---------------- fold_W: Wc = tw1@T, bc = tb1@T + bc2 + c1b --------------
__global__ __launch_bounds__(256) void fold_W(const float* __restrict__ tw1,
                                              const float* __restrict__ T,
                                              const float* __restrict__ tb1,
                                              const float* __restrict__ bc2,
                                              const float* __restrict__ c1b,
                                              float* __restrict__ Wc,
                                              float* __restrict__ bc) {
    const int b = blockIdx.x;
    const int t = threadIdx.x;
    if (b < 64) {
        const int r = b * 4 + (t >> 6);
        const int cth = t & 63;
        float s = 0.0f;
        for (int j = 0; j < CC; ++j) s = fmaf(tw1[r * CC + j], T[j * 64 + cth], s);
        Wc[r * 64 + cth] = s;
    } else if (t < 64) {
        float s = 0.0f;
        for (int j = 0; j < CC; ++j) s = fmaf(tb1[j], T[j * 64 + t], s);
        bc[t] = s + bc2[t] + c1b[t];
    }
}

// ---------------- CSR build (by dst) ----------------
__global__ void csr_hist(const int* __restrict__ dst, int* cnt) {
    int e = blockIdx.x * 256 + threadIdx.x;
    if (e < EG) atomicAdd(&cnt[dst[e]], 1);
}
__global__ __launch_bounds__(1024) void csr_scan(const int* __restrict__ cnt,
                                                 int* __restrict__ rowp,
                                                 int* __restrict__ cur) {
    __shared__ int tmp[1024];
    const int t = threadIdx.x;
    const int base = t * 32;
    int local[32];
    int s = 0;
#pragma unroll
    for (int i = 0; i < 32; ++i) { local[i] = s; s += cnt[base + i]; }
    tmp[t] = s;
    __syncthreads();
    for (int o = 1; o < 1024; o <<= 1) {
        int v = (t >= o) ? tmp[t - o] : 0;
        __syncthreads();
        tmp[t] += v;
        __syncthreads();
    }
    int off = tmp[t] - s;  // exclusive prefix
#pragma unroll
    for (int i = 0; i < 32; ++i) {
        int p = off + local[i];
        rowp[base + i] = p;
        cur[base + i] = p;
    }
    if (t == 1023) rowp[NN] = off + s;
}
__global__ void csr_scatter(const int* __restrict__ src, const int* __restrict__ dst,
                            int* cur, int* __restrict__ esrc) {
    int e = blockIdx.x * 256 + threadIdx.x;
    if (e < EG) {
        int p = atomicAdd(&cur[dst[e]], 1);
        esrc[p] = src[e];
    }
}

// ---------------- fused GAT edge stage: softmax + aggregate + ELU ----------
// One wave per dst node, 4 waves/block, no barriers, XCD-swizzled.
// Optional epilogues: bf16 split write (layer 1) / fp32 + scores (layer 2).
__global__ __launch_bounds__(256) void gat_edge(const float* __restrict__ z,
                                                const int* __restrict__ rowp,
                                                const int* __restrict__ esrc,
                                                const float* __restrict__ es,
                                                const float* __restrict__ ed,
                                                const float* __restrict__ bias,
                                                float* __restrict__ out,
                                                unsigned short* __restrict__ outh,
                                                unsigned short* __restrict__ outl,
                                                const float* __restrict__ sw1,
                                                const float* __restrict__ sb1,
                                                const float* __restrict__ w12,
                                                const float* __restrict__ b12,
                                                float* __restrict__ sc1,
                                                float* __restrict__ sc2) {
    const int w = threadIdx.x >> 6;
    const int l = threadIdx.x & 63;
    const int b    = blockIdx.x;              // 0..8191
    const int xcd  = b & 7;
    const int slot = b >> 3;                  // 0..1023
    const int gph  = xcd + ((slot >> 7) << 3);
    const int d    = gph * NPG + ((slot & 127) << 2) + w;

    const int h  = l & 3;
    const int ei = l >> 2;
    const int h2 = l >> 4;
    const int beg = rowp[d];
    const int deg = rowp[d + 1] - beg;

    const float4 zv = *(const float4*)(z + (size_t)d * CC + 4 * l);
    float4 acc;

    if (deg <= 16 * NS) {
        // ---- phase A: register softmax ----
        const float edh = ed[d * HH + h];
        int   sidx[NS];
        float v[NS];
        float vmax = -INFINITY, eself = 0.0f;
        float vself = 0.0f;
        if (ei == 0) {
            vself = leaky02(es[d * HH + h] + edh);
            vmax = vself;
        }
#pragma unroll
        for (int j = 0; j < NS; ++j) {
            int i = ei + 16 * j;
            if (i < deg) {
                sidx[j] = esrc[beg + i];
                v[j] = leaky02(es[sidx[j] * HH + h] + edh);
                vmax = fmaxf(vmax, v[j]);
            }
        }
#pragma unroll
        for (int o = 4; o <= 32; o <<= 1) vmax = fmaxf(vmax, __shfl_xor(vmax, o));
        float dsum = 0.0f;
#pragma unroll
        for (int j = 0; j < NS; ++j) {
            int i = ei + 16 * j;
            if (i < deg) { v[j] = __expf(v[j] - vmax); dsum += v[j]; }
        }
        if (ei == 0) { eself = __expf(vself - vmax); dsum += eself; }
#pragma unroll
        for (int o = 4; o <= 32; o <<= 1) dsum += __shfl_xor(dsum, o);
        const float inv = 1.0f / (dsum + 1e-16f);
#pragma unroll
        for (int j = 0; j < NS; ++j) v[j] *= inv;   // normalized alpha
        eself *= inv;

        // ---- phase B: float4 aggregation ----
        float aself = __shfl(eself, h2);
        acc = make_float4(aself * zv.x, aself * zv.y, aself * zv.z, aself * zv.w);
#pragma unroll
        for (int j = 0; j < NS; ++j) {
            if (16 * j < deg) {
                for (int s = 0; s < 16; ++s) {
                    int i = 16 * j + s;
                    if (i >= deg) break;
                    int   srcn = __shfl(sidx[j], s * 4);
                    float a    = __shfl(v[j],    s * 4 + h2);
                    float4 zs  = *(const float4*)(z + (size_t)srcn * CC + 4 * l);
                    acc.x = fmaf(a, zs.x, acc.x);
                    acc.y = fmaf(a, zs.y, acc.y);
                    acc.z = fmaf(a, zs.z, acc.z);
                    acc.w = fmaf(a, zs.w, acc.w);
                }
            }
        }
    } else {
        // ---- generic slow path (never taken for the fixed input) ----
        const float edh = ed[d * HH + h];
        float vmax = (ei == 0) ? leaky02(es[d * HH + h] + edh) : -INFINITY;
        for (int i = ei; i < deg; i += 16)
            vmax = fmaxf(vmax, leaky02(es[esrc[beg + i] * HH + h] + edh));
#pragma unroll
        for (int o = 4; o <= 32; o <<= 1) vmax = fmaxf(vmax, __shfl_xor(vmax, o));
        float dsum = (ei == 0) ? __expf(leaky02(es[d * HH + h] + edh) - vmax) : 0.0f;
        for (int i = ei; i < deg; i += 16)
            dsum += __expf(leaky02(es[esrc[beg + i] * HH + h] + edh) - vmax);
#pragma unroll
        for (int o = 4; o <= 32; o <<= 1) dsum += __shfl_xor(dsum, o);
        const float inv = 1.0f / (dsum + 1e-16f);

        const float vmaxc = __shfl(vmax, h2);
        const float invc  = __shfl(inv,  h2);
        const float edh4  = ed[d * HH + h2];
        float a0 = __expf(leaky02(es[d * HH + h2] + edh4) - vmaxc) * invc;
        acc = make_float4(a0 * zv.x, a0 * zv.y, a0 * zv.z, a0 * zv.w);
        for (int i = 0; i < deg; ++i) {
            int srcn = esrc[beg + i];
            float a = __expf(leaky02(es[srcn * HH + h2] + edh4) - vmaxc) * invc;
            float4 zs = *(const float4*)(z + (size_t)srcn * CC + 4 * l);
            acc.x = fmaf(a, zs.x, acc.x);
            acc.y = fmaf(a, zs.y, acc.y);
            acc.z = fmaf(a, zs.z, acc.z);
            acc.w = fmaf(a, zs.w, acc.w);
        }
    }

    // ---- epilogue: bias + ELU ----
    const float4 bv = *(const float4*)(bias + 4 * l);
    float4 o;
    o.x = acc.x + bv.x; o.x = o.x > 0.0f ? o.x : expm1f(o.x);
    o.y = acc.y + bv.y; o.y = o.y > 0.0f ? o.y : expm1f(o.y);
    o.z = acc.z + bv.z; o.z = o.z > 0.0f ? o.z : expm1f(o.z);
    o.w = acc.w + bv.w; o.w = o.w > 0.0f ? o.w : expm1f(o.w);

    if (out) *(float4*)(out + (size_t)d * CC + 4 * l) = o;
    if (outh) {   // bf16 split write (feeds next layer's MFMA GEMM)
        ushort4 uh, ul;
        split2(o.x, uh.x, ul.x);
        split2(o.y, uh.y, ul.y);
        split2(o.z, uh.z, ul.z);
        split2(o.w, uh.w, ul.w);
        ((ushort4*)outh)[(size_t)d * 64 + l] = uh;
        ((ushort4*)outl)[(size_t)d * 64 + l] = ul;
    }

    if (sc1) {
        const float4 s1 = *(const float4*)(sw1 + 4 * l);
        const float4 s2 = *(const float4*)(w12 + 4 * l);
        float r1 = o.x * s1.x + o.y * s1.y + o.z * s1.z + o.w * s1.w;
        float r2 = o.x * s2.x + o.y * s2.y + o.z * s2.z + o.w * s2.w;
#pragma unroll
        for (int off = 32; off >= 1; off >>= 1) {
            r1 += __shfl_xor(r1, off);
            r2 += __shfl_xor(r2, off);
        }
        if (l == 0) {
            sc1[d] = r1 + sb1[0];
            sc2[d] = r2 + b12[0];
        }
    }
}

// ---------------- fused pooling + folded head (one block per graph) -------
__global__ __launch_bounds__(512) void pool_head(const float* __restrict__ feat,
                                                 const float* __restrict__ sc1,
                                                 const float* __restrict__ sc2,
                                                 const float* __restrict__ Wc,
                                                 const float* __restrict__ bc,
                                                 const float* __restrict__ c2w,
                                                 const float* __restrict__ c2b,
                                                 float* __restrict__ out) {
    __shared__ float s[NPG];
    __shared__ unsigned char keep[NPG];
    __shared__ float vbuf[8][CC];
    __shared__ float v0[CC];
    __shared__ float part[8][64];
    __shared__ float v2[64];
    const int g = blockIdx.x;
    const int i = threadIdx.x;

    // ---- top-k1 (rank counting; lower index wins ties) ----
    float my = sc1[g * NPG + i];
    s[i] = my;
    __syncthreads();
    int rank = 0;
    for (int j = 0; j < NPG; ++j) {
        float sj = s[j];
        rank += (sj > my) || (sj == my && j < i);
    }
    int k1 = rank < KP1;
    __syncthreads();
    // ---- top-k2 restricted to k1 set ----
    float my2 = k1 ? sc2[g * NPG + i] : -INFINITY;
    s[i] = my2;
    __syncthreads();
    rank = 0;
    for (int j = 0; j < NPG; ++j) {
        float sj = s[j];
        rank += (sj > my2) || (sj == my2 && j < i);
    }
    keep[i] = (unsigned char)(k1 && rank < KP2);
    __syncthreads();

    // ---- masked mean, float4 ----
    const int r = i >> 6, c4 = i & 63;
    float4 acc = make_float4(0.0f, 0.0f, 0.0f, 0.0f);
    const float4* f4 = (const float4*)(feat + (size_t)g * NPG * CC);
    for (int j = r; j < NPG; j += 8) {
        if (keep[j]) {
            float4 v = f4[j * 64 + c4];
            acc.x += v.x; acc.y += v.y; acc.z += v.z; acc.w += v.w;
        }
    }
    vbuf[r][c4 * 4 + 0] = acc.x;
    vbuf[r][c4 * 4 + 1] = acc.y;
    vbuf[r][c4 * 4 + 2] = acc.z;
    vbuf[r][c4 * 4 + 3] = acc.w;
    __syncthreads();
    if (i < CC) {
        float t = 0.0f;
#pragma unroll
        for (int q = 0; q < 8; ++q) t += vbuf[q][i];
        v0[i] = t * (1.0f / KP2);
    }
    __syncthreads();

    // ---- u = relu(v0 @ Wc + bc), split j-sum 8 ways ----
    {
        const int q = i >> 6, cth = i & 63;
        float p = 0.0f;
        for (int j = q * 32; j < q * 32 + 32; ++j)
            p = fmaf(v0[j], Wc[j * 64 + cth], p);
        part[q][cth] = p;
    }
    __syncthreads();
    if (i < 64) {
        float u = bc[i];
#pragma unroll
        for (int q = 0; q < 8; ++q) u += part[q][i];
        v2[i] = fmaxf(u, 0.0f);
    }
    __syncthreads();
    if (i < 2) {
        float o = c2b[i];
        for (int j = 0; j < 64; ++j) o = fmaf(v2[j], c2w[j * 2 + i], o);
        s[i] = o;
    }
    __syncthreads();
    if (i == 0) {
        float a = s[0], bq = s[1];
        float mx = fmaxf(a, bq);
        float lse = mx + logf(expf(a - mx) + expf(bq - mx));
        out[g * 2 + 0] = a - lse;
        out[g * 2 + 1] = bq - lse;
    }
}

// ---------------- launcher ----------------
extern "C" void kernel_launch(void* const* d_in, const int* in_sizes, int n_in,
                              void* d_out, int out_size, void* d_ws, size_t ws_size,
                              hipStream_t stream) {
    const float* x      = (const float*)d_in[0];
    const int*   ei     = (const int*)d_in[1];
    const int*   src    = ei;
    const int*   dst    = ei + EG;
    const float* W1     = (const float*)d_in[3];
    const float* a_src1 = (const float*)d_in[4];
    const float* a_dst1 = (const float*)d_in[5];
    const float* b1     = (const float*)d_in[6];
    const float* W2     = (const float*)d_in[7];
    const float* a_src2 = (const float*)d_in[8];
    const float* a_dst2 = (const float*)d_in[9];
    const float* b2     = (const float*)d_in[10];
    const float* p1_sw  = (const float*)d_in[11];
    const float* p1_sb  = (const float*)d_in[12];
    const float* p1_tw  = (const float*)d_in[13];
    const float* p1_tb  = (const float*)d_in[14];
    const float* p2_sw  = (const float*)d_in[15];
    const float* p2_sb  = (const float*)d_in[16];
    const float* p2_tw  = (const float*)d_in[17];
    const float* p2_tb  = (const float*)d_in[18];
    const float* c1w    = (const float*)d_in[19];
    const float* c1b    = (const float*)d_in[20];
    const float* c2w    = (const float*)d_in[21];
    const float* c2b    = (const float*)d_in[22];
    float* out = (float*)d_out;

    // workspace layout
    float* ws = (float*)d_ws;
    unsigned short* xhi = (unsigned short*)ws;          // NN*FIN ushorts
    unsigned short* xlo = xhi + (size_t)NN * FIN;       // NN*FIN
    float* z = ws + (size_t)NN * FIN;                   // NN*CC floats
    float* fregion = z + (size_t)NN * CC;               // NN*CC floats (32 MB)
    unsigned short* fhi = (unsigned short*)fregion;     //   phase 1: fhi/flo bf16
    unsigned short* flo = fhi + (size_t)NN * CC;
    float* featF = fregion;                             //   phase 2: fp32 feat (alias)
    float* wsp = fregion + (size_t)NN * CC;
    unsigned short* w1th = (unsigned short*)wsp;        // 256*128
    unsigned short* w1tl = w1th + 256 * FIN;
    unsigned short* w2th = w1tl + 256 * FIN;            // 256*256
    unsigned short* w2tl = w2th + 256 * CC;
    float* es  = (float*)(w2tl + 256 * CC);             // N*H
    float* ed  = es + NN * HH;
    int* cnt   = (int*)(ed + NN * HH);                  // N
    int* rowp  = cnt + NN;                              // N+1
    int* cur   = rowp + NN + 1;                         // N
    int* esrc  = cur + NN;                              // E
    float* sc1 = (float*)(esrc + EG);                   // N
    float* sc2 = sc1 + NN;
    float* w12 = sc2 + NN;                              // C
    float* b12 = w12 + CC;                              // 1 (padded 64)
    float* T   = b12 + 64;                              // 256*64
    float* Wc  = T + CC * 64;                           // 256*64
    float* bc2 = Wc + CC * 64;                          // 64
    float* bcv = bc2 + 64;                              // 64

    // ---- prep + conversions + CSR build ----
    prep<<<194, 256, 0, stream>>>(cnt, p1_tw, p2_sw, p1_tb, p2_sb, w12, b12,
                                  p2_tw, c1w, p2_tb, T, bc2);
    conv_split<<<(NN * FIN / 4 + 255) / 256, 256, 0, stream>>>(x, xhi, xlo, NN * FIN / 4);
    conv_wT<<<(256 * FIN + 256 * CC) / 256, 256, 0, stream>>>(W1, W2, w1th, w1tl, w2th, w2tl);
    csr_hist<<<(EG + 255) / 256, 256, 0, stream>>>(dst, cnt);
    csr_scan<<<1, 1024, 0, stream>>>(cnt, rowp, cur);
    csr_scatter<<<(EG + 255) / 256, 256, 0, stream>>>(src, dst, cur, esrc);
    fold_W<<<65, 256, 0, stream>>>(p1_tw, T, p1_tb, bc2, c1b, Wc, bcv);

    // ---- GAT layer 1 (MFMA gemm -> z,es,ed; edge stage -> fhi/flo) ----
    gemm_mfma_attn<<<NN / 16, 256, 0, stream>>>(xhi, xlo, w1th, w1tl, z, FIN,
                                                a_src1, a_dst1, es, ed);
    gat_edge<<<NN / 4, 256, 0, stream>>>(z, rowp, esrc, es, ed, b1,
                                         nullptr, fhi, flo,
                                         nullptr, nullptr, nullptr, nullptr,
                                         nullptr, nullptr);

    // ---- GAT layer 2 (MFMA gemm on split feat; scores fused) ----
    gemm_mfma_attn<<<NN / 16, 256, 0, stream>>>(fhi, flo, w2th, w2tl, z, CC,
                                                a_src2, a_dst2, es, ed);
    gat_edge<<<NN / 4, 256, 0, stream>>>(z, rowp, esrc, es, ed, b2,
                                         featF, nullptr, nullptr,
                                         p1_sw, p1_sb, w12, b12, sc1, sc2);

    // ---- fused pooling + folded head ----
    pool_head<<<BG, 512, 0, stream>>>(featF, sc1, sc2, Wc, bcv, c2w, c2b, out);
}

// Round 10
// 355.252 us; speedup vs baseline: 1.1723x; 1.1723x over previous
//
#include <hip/hip_runtime.h>
#include <hip/hip_bf16.h>
#include <math.h>

// ---------------- problem constants ----------------
constexpr int NN  = 32768;   // nodes
constexpr int BG  = 64;      // graphs
constexpr int NPG = 512;     // nodes per graph
constexpr int EG  = 524288;  // edges
constexpr int HH  = 4;       // heads
constexpr int FH  = 64;      // per-head dim
constexpr int CC  = 256;     // H*Fh
constexpr int FIN = 128;
constexpr int KP1 = 256;     // pool1 k
constexpr int KP2 = 128;     // pool2 k
constexpr int NS  = 4;       // register edge slots: fast path deg <= 64

typedef __attribute__((ext_vector_type(8))) short short8;  // 8 bf16 = 4 VGPRs
typedef __attribute__((ext_vector_type(4))) float f32x4;

__device__ inline float leaky02(float v) { return v > 0.0f ? v : 0.2f * v; }

__device__ inline unsigned short f2bf(float v) {
    __hip_bfloat16 h = __float2bfloat16(v);
    return *(unsigned short*)&h;
}
__device__ inline float bf2f(unsigned short u) {
    __hip_bfloat16 h;
    *(unsigned short*)&h = u;
    return __bfloat162float(h);
}
__device__ inline void split2(float v, unsigned short& hi, unsigned short& lo) {
    hi = f2bf(v);
    lo = f2bf(v - bf2f(hi));
}

// ---------------- split-precision conversion kernels ----------------------
// x fp32 -> (hi,lo) bf16 row-major, 4 elems/thread
__global__ __launch_bounds__(256) void conv_split(const float* __restrict__ X,
                                                  unsigned short* __restrict__ Hi,
                                                  unsigned short* __restrict__ Lo,
                                                  int n4) {
    int i = blockIdx.x * 256 + threadIdx.x;
    if (i >= n4) return;
    float4 v = ((const float4*)X)[i];
    ushort4 h, l;
    split2(v.x, h.x, l.x);
    split2(v.y, h.y, l.y);
    split2(v.z, h.z, l.z);
    split2(v.w, h.w, l.w);
    ((ushort4*)Hi)[i] = h;
    ((ushort4*)Lo)[i] = l;
}

// W1 [128x256], W2 [256x256] fp32 -> FRAGMENT-PACKED split bf16.
// Packed layout: [nt (16 cols)][kg (32 k)][lane l][j]:
//   n = nt*16 + (l&15), k = kg*32 + (l>>4)*8 + j
// -> GEMM B-fragment load = one coalesced 1KB wave load.
__global__ __launch_bounds__(256) void conv_wpack(const float* __restrict__ W1,
                                                  const float* __restrict__ W2,
                                                  unsigned short* __restrict__ w1ph,
                                                  unsigned short* __restrict__ w1pl,
                                                  unsigned short* __restrict__ w2ph,
                                                  unsigned short* __restrict__ w2pl) {
    int idx = blockIdx.x * 256 + threadIdx.x;      // 0 .. 12287
    if (idx < 4096) {                              // W1: 16 nt x 4 kg x 64 l
        const int nt = idx >> 8, rem = idx & 255;
        const int kg = rem >> 6, l = rem & 63;
        const int n = nt * 16 + (l & 15);
        const int kb = kg * 32 + (l >> 4) * 8;
        unsigned short h[8], lo[8];
#pragma unroll
        for (int j = 0; j < 8; ++j) split2(W1[(kb + j) * CC + n], h[j], lo[j]);
#pragma unroll
        for (int j = 0; j < 8; ++j) {
            w1ph[(size_t)idx * 8 + j] = h[j];
            w1pl[(size_t)idx * 8 + j] = lo[j];
        }
    } else if (idx < 12288) {                      // W2: 16 nt x 8 kg x 64 l
        const int i2 = idx - 4096;
        const int nt = i2 >> 9, rem = i2 & 511;
        const int kg = rem >> 6, l = rem & 63;
        const int n = nt * 16 + (l & 15);
        const int kb = kg * 32 + (l >> 4) * 8;
        unsigned short h[8], lo[8];
#pragma unroll
        for (int j = 0; j < 8; ++j) split2(W2[(kb + j) * CC + n], h[j], lo[j]);
#pragma unroll
        for (int j = 0; j < 8; ++j) {
            w2ph[(size_t)i2 * 8 + j] = h[j];
            w2pl[(size_t)i2 * 8 + j] = lo[j];
        }
    }
}

// ---------------- MFMA GEMM: C[M,256] = A[M,K]@B[K,256], split-bf16 -------
// Block = 32 rows x 256 cols (2 row-subtiles), 4 waves; wave w = head w owns
// cols w*64..+63 (4 col-tiles). 1024 blocks (4/CU). No LDS, no barriers.
// B from fragment-packed layout (coalesced 1KB wave loads, L2-resident).
// A row-major bf16 (read-once, L1). acc = Ahi*Bhi + Ahi*Blo + Alo*Bhi.
__global__ __launch_bounds__(256, 4) void gemm_mfma_attn(
        const unsigned short* __restrict__ Ahi, const unsigned short* __restrict__ Alo,
        const unsigned short* __restrict__ Bph, const unsigned short* __restrict__ Bpl,
        float* __restrict__ Cm, int K,
        const float* __restrict__ a_src, const float* __restrict__ a_dst,
        float* __restrict__ es, float* __restrict__ ed) {
    const int t = threadIdx.x;
    const int w = t >> 6;          // wave = col strip = head
    const int l = t & 63;
    const int bx   = blockIdx.x;               // 0..1023
    const int xcd  = bx & 7;
    const int slot = bx >> 3;                  // 0..127
    const int gph  = xcd + ((slot >> 4) << 3); // graph
    const int row0 = gph * NPG + ((slot & 15) << 5);
    const int m = l & 15;
    const int q = l >> 4;
    const int ncol0 = w * 64;
    const int KG = K >> 5;

    const unsigned short* aH0 = Ahi + (size_t)(row0 + m) * K + q * 8;
    const unsigned short* aL0 = Alo + (size_t)(row0 + m) * K + q * 8;
    const unsigned short* aH1 = aH0 + (size_t)16 * K;
    const unsigned short* aL1 = aL0 + (size_t)16 * K;

    f32x4 acc0[4], acc1[4];
#pragma unroll
    for (int c = 0; c < 4; ++c) {
        acc0[c] = (f32x4){0.f, 0.f, 0.f, 0.f};
        acc1[c] = (f32x4){0.f, 0.f, 0.f, 0.f};
    }

    for (int kg = 0; kg < KG; ++kg) {
        const int ko = kg * 32;
        short8 ah0 = *(const short8*)(aH0 + ko);
        short8 al0 = *(const short8*)(aL0 + ko);
        short8 ah1 = *(const short8*)(aH1 + ko);
        short8 al1 = *(const short8*)(aL1 + ko);
#pragma unroll
        for (int c = 0; c < 4; ++c) {
            const int nt = (w << 2) + c;
            const size_t boff = ((size_t)(nt * KG + kg) * 64 + l) * 8;
            short8 bh = *(const short8*)(Bph + boff);
            short8 bl = *(const short8*)(Bpl + boff);
            acc0[c] = __builtin_amdgcn_mfma_f32_16x16x32_bf16(ah0, bh, acc0[c], 0, 0, 0);
            acc0[c] = __builtin_amdgcn_mfma_f32_16x16x32_bf16(ah0, bl, acc0[c], 0, 0, 0);
            acc0[c] = __builtin_amdgcn_mfma_f32_16x16x32_bf16(al0, bh, acc0[c], 0, 0, 0);
            acc1[c] = __builtin_amdgcn_mfma_f32_16x16x32_bf16(ah1, bh, acc1[c], 0, 0, 0);
            acc1[c] = __builtin_amdgcn_mfma_f32_16x16x32_bf16(ah1, bl, acc1[c], 0, 0, 0);
            acc1[c] = __builtin_amdgcn_mfma_f32_16x16x32_bf16(al1, bh, acc1[c], 0, 0, 0);
        }
    }

    // ---- C store ----
#pragma unroll
    for (int c = 0; c < 4; ++c)
#pragma unroll
        for (int r = 0; r < 4; ++r) {
            Cm[(size_t)(row0 + q * 4 + r) * CC + ncol0 + c * 16 + m] = acc0[c][r];
            Cm[(size_t)(row0 + 16 + q * 4 + r) * CC + ncol0 + c * 16 + m] = acc1[c][r];
        }

    // ---- es/ed epilogue: head w ----
    float asv[4], adv[4];
#pragma unroll
    for (int c = 0; c < 4; ++c) {
        asv[c] = a_src[ncol0 + c * 16 + m];
        adv[c] = a_dst[ncol0 + c * 16 + m];
    }
#pragma unroll
    for (int r = 0; r < 4; ++r) {
        float ps0 = 0.f, pd0 = 0.f, ps1 = 0.f, pd1 = 0.f;
#pragma unroll
        for (int c = 0; c < 4; ++c) {
            ps0 = fmaf(acc0[c][r], asv[c], ps0);
            pd0 = fmaf(acc0[c][r], adv[c], pd0);
            ps1 = fmaf(acc1[c][r], asv[c], ps1);
            pd1 = fmaf(acc1[c][r], adv[c], pd1);
        }
#pragma unroll
        for (int o = 8; o >= 1; o >>= 1) {
            ps0 += __shfl_down(ps0, o, 16);
            pd0 += __shfl_down(pd0, o, 16);
            ps1 += __shfl_down(ps1, o, 16);
            pd1 += __shfl_down(pd1, o, 16);
        }
        if (m == 0) {
            es[(row0 + q * 4 + r) * HH + w] = ps0;
            ed[(row0 + q * 4 + r) * HH + w] = pd0;
            es[(row0 + 16 + q * 4 + r) * HH + w] = ps1;
            ed[(row0 + 16 + q * 4 + r) * HH + w] = pd1;
        }
    }
}

// ---------------- prep: zero cnt + w12 + T = tw2@c1w + bc2 = tb2@c1w -------
__global__ __launch_bounds__(256) void prep(int* __restrict__ cnt,
                                            const float* __restrict__ tw1,
                                            const float* __restrict__ sw2,
                                            const float* __restrict__ tb1,
                                            const float* __restrict__ sb2,
                                            float* __restrict__ w12,
                                            float* __restrict__ b12,
                                            const float* __restrict__ tw2,
                                            const float* __restrict__ c1w,
                                            const float* __restrict__ tb2,
                                            float* __restrict__ T,
                                            float* __restrict__ bc2) {
    const int b = blockIdx.x;
    const int t = threadIdx.x;
    if (b < 128) {
        cnt[b * 256 + t] = 0;
    } else if (b == 128) {
        float s = 0.0f;
        for (int o = 0; o < CC; ++o) s += tw1[t * CC + o] * sw2[o];
        w12[t] = s;
        if (t == 0) {
            float bb = 0.0f;
            for (int o = 0; o < CC; ++o) bb += tb1[o] * sw2[o];
            *b12 = bb + sb2[0];
        }
    } else if (b < 193) {
        const int r = (b - 129) * 4 + (t >> 6);
        const int cth = t & 63;
        float s = 0.0f;
        for (int j = 0; j < CC; ++j) s = fmaf(tw2[r * CC + j], c1w[j * 64 + cth], s);
        T[r * 64 + cth] = s;
    } else if (t < 64) {
        float s = 0.0f;
        for (int j = 0; j < CC; ++j) s = fmaf(tb2[j], c1w[j * 64 + t], s);
        bc2[t] = s;
    }
}

// ---------------- fold_W: Wc = tw1@T, bc = tb1@T + bc2 + c1b --------------
__global__ __launch_bounds__(256) void fold_W(const float* __restrict__ tw1,
                                              const float* __restrict__ T,
                                              const float* __restrict__ tb1,
                                              const float* __restrict__ bc2,
                                              const float* __restrict__ c1b,
                                              float* __restrict__ Wc,
                                              float* __restrict__ bc) {
    const int b = blockIdx.x;
    const int t = threadIdx.x;
    if (b < 64) {
        const int r = b * 4 + (t >> 6);
        const int cth = t & 63;
        float s = 0.0f;
        for (int j = 0; j < CC; ++j) s = fmaf(tw1[r * CC + j], T[j * 64 + cth], s);
        Wc[r * 64 + cth] = s;
    } else if (t < 64) {
        float s = 0.0f;
        for (int j = 0; j < CC; ++j) s = fmaf(tb1[j], T[j * 64 + t], s);
        bc[t] = s + bc2[t] + c1b[t];
    }
}

// ---------------- CSR build (by dst) ----------------
__global__ void csr_hist(const int* __restrict__ dst, int* cnt) {
    int e = blockIdx.x * 256 + threadIdx.x;
    if (e < EG) atomicAdd(&cnt[dst[e]], 1);
}
__global__ __launch_bounds__(1024) void csr_scan(const int* __restrict__ cnt,
                                                 int* __restrict__ rowp,
                                                 int* __restrict__ cur) {
    __shared__ int tmp[1024];
    const int t = threadIdx.x;
    const int base = t * 32;
    int local[32];
    int s = 0;
#pragma unroll
    for (int i = 0; i < 32; ++i) { local[i] = s; s += cnt[base + i]; }
    tmp[t] = s;
    __syncthreads();
    for (int o = 1; o < 1024; o <<= 1) {
        int v = (t >= o) ? tmp[t - o] : 0;
        __syncthreads();
        tmp[t] += v;
        __syncthreads();
    }
    int off = tmp[t] - s;  // exclusive prefix
#pragma unroll
    for (int i = 0; i < 32; ++i) {
        int p = off + local[i];
        rowp[base + i] = p;
        cur[base + i] = p;
    }
    if (t == 1023) rowp[NN] = off + s;
}
__global__ void csr_scatter(const int* __restrict__ src, const int* __restrict__ dst,
                            int* cur, int* __restrict__ esrc) {
    int e = blockIdx.x * 256 + threadIdx.x;
    if (e < EG) {
        int p = atomicAdd(&cur[dst[e]], 1);
        esrc[p] = src[e];
    }
}

// ---------------- fused GAT edge stage: softmax + aggregate + ELU ----------
__global__ __launch_bounds__(256) void gat_edge(const float* __restrict__ z,
                                                const int* __restrict__ rowp,
                                                const int* __restrict__ esrc,
                                                const float* __restrict__ es,
                                                const float* __restrict__ ed,
                                                const float* __restrict__ bias,
                                                float* __restrict__ out,
                                                unsigned short* __restrict__ outh,
                                                unsigned short* __restrict__ outl,
                                                const float* __restrict__ sw1,
                                                const float* __restrict__ sb1,
                                                const float* __restrict__ w12,
                                                const float* __restrict__ b12,
                                                float* __restrict__ sc1,
                                                float* __restrict__ sc2) {
    const int w = threadIdx.x >> 6;
    const int l = threadIdx.x & 63;
    const int b    = blockIdx.x;              // 0..8191
    const int xcd  = b & 7;
    const int slot = b >> 3;                  // 0..1023
    const int gph  = xcd + ((slot >> 7) << 3);
    const int d    = gph * NPG + ((slot & 127) << 2) + w;

    const int h  = l & 3;
    const int ei = l >> 2;
    const int h2 = l >> 4;
    const int beg = rowp[d];
    const int deg = rowp[d + 1] - beg;

    const float4 zv = *(const float4*)(z + (size_t)d * CC + 4 * l);
    float4 acc;

    if (deg <= 16 * NS) {
        const float edh = ed[d * HH + h];
        int   sidx[NS];
        float v[NS];
        float vmax = -INFINITY, eself = 0.0f;
        float vself = 0.0f;
        if (ei == 0) {
            vself = leaky02(es[d * HH + h] + edh);
            vmax = vself;
        }
#pragma unroll
        for (int j = 0; j < NS; ++j) {
            int i = ei + 16 * j;
            if (i < deg) {
                sidx[j] = esrc[beg + i];
                v[j] = leaky02(es[sidx[j] * HH + h] + edh);
                vmax = fmaxf(vmax, v[j]);
            }
        }
#pragma unroll
        for (int o = 4; o <= 32; o <<= 1) vmax = fmaxf(vmax, __shfl_xor(vmax, o));
        float dsum = 0.0f;
#pragma unroll
        for (int j = 0; j < NS; ++j) {
            int i = ei + 16 * j;
            if (i < deg) { v[j] = __expf(v[j] - vmax); dsum += v[j]; }
        }
        if (ei == 0) { eself = __expf(vself - vmax); dsum += eself; }
#pragma unroll
        for (int o = 4; o <= 32; o <<= 1) dsum += __shfl_xor(dsum, o);
        const float inv = 1.0f / (dsum + 1e-16f);
#pragma unroll
        for (int j = 0; j < NS; ++j) v[j] *= inv;
        eself *= inv;

        float aself = __shfl(eself, h2);
        acc = make_float4(aself * zv.x, aself * zv.y, aself * zv.z, aself * zv.w);
#pragma unroll
        for (int j = 0; j < NS; ++j) {
            if (16 * j < deg) {
                for (int s = 0; s < 16; ++s) {
                    int i = 16 * j + s;
                    if (i >= deg) break;
                    int   srcn = __shfl(sidx[j], s * 4);
                    float a    = __shfl(v[j],    s * 4 + h2);
                    float4 zs  = *(const float4*)(z + (size_t)srcn * CC + 4 * l);
                    acc.x = fmaf(a, zs.x, acc.x);
                    acc.y = fmaf(a, zs.y, acc.y);
                    acc.z = fmaf(a, zs.z, acc.z);
                    acc.w = fmaf(a, zs.w, acc.w);
                }
            }
        }
    } else {
        const float edh = ed[d * HH + h];
        float vmax = (ei == 0) ? leaky02(es[d * HH + h] + edh) : -INFINITY;
        for (int i = ei; i < deg; i += 16)
            vmax = fmaxf(vmax, leaky02(es[esrc[beg + i] * HH + h] + edh));
#pragma unroll
        for (int o = 4; o <= 32; o <<= 1) vmax = fmaxf(vmax, __shfl_xor(vmax, o));
        float dsum = (ei == 0) ? __expf(leaky02(es[d * HH + h] + edh) - vmax) : 0.0f;
        for (int i = ei; i < deg; i += 16)
            dsum += __expf(leaky02(es[esrc[beg + i] * HH + h] + edh) - vmax);
#pragma unroll
        for (int o = 4; o <= 32; o <<= 1) dsum += __shfl_xor(dsum, o);
        const float inv = 1.0f / (dsum + 1e-16f);

        const float vmaxc = __shfl(vmax, h2);
        const float invc  = __shfl(inv,  h2);
        const float edh4  = ed[d * HH + h2];
        float a0 = __expf(leaky02(es[d * HH + h2] + edh4) - vmaxc) * invc;
        acc = make_float4(a0 * zv.x, a0 * zv.y, a0 * zv.z, a0 * zv.w);
        for (int i = 0; i < deg; ++i) {
            int srcn = esrc[beg + i];
            float a = __expf(leaky02(es[srcn * HH + h2] + edh4) - vmaxc) * invc;
            float4 zs = *(const float4*)(z + (size_t)srcn * CC + 4 * l);
            acc.x = fmaf(a, zs.x, acc.x);
            acc.y = fmaf(a, zs.y, acc.y);
            acc.z = fmaf(a, zs.z, acc.z);
            acc.w = fmaf(a, zs.w, acc.w);
        }
    }

    const float4 bv = *(const float4*)(bias + 4 * l);
    float4 o;
    o.x = acc.x + bv.x; o.x = o.x > 0.0f ? o.x : expm1f(o.x);
    o.y = acc.y + bv.y; o.y = o.y > 0.0f ? o.y : expm1f(o.y);
    o.z = acc.z + bv.z; o.z = o.z > 0.0f ? o.z : expm1f(o.z);
    o.w = acc.w + bv.w; o.w = o.w > 0.0f ? o.w : expm1f(o.w);

    if (out) *(float4*)(out + (size_t)d * CC + 4 * l) = o;
    if (outh) {
        ushort4 uh, ul;
        split2(o.x, uh.x, ul.x);
        split2(o.y, uh.y, ul.y);
        split2(o.z, uh.z, ul.z);
        split2(o.w, uh.w, ul.w);
        ((ushort4*)outh)[(size_t)d * 64 + l] = uh;
        ((ushort4*)outl)[(size_t)d * 64 + l] = ul;
    }

    if (sc1) {
        const float4 s1 = *(const float4*)(sw1 + 4 * l);
        const float4 s2 = *(const float4*)(w12 + 4 * l);
        float r1 = o.x * s1.x + o.y * s1.y + o.z * s1.z + o.w * s1.w;
        float r2 = o.x * s2.x + o.y * s2.y + o.z * s2.z + o.w * s2.w;
#pragma unroll
        for (int off = 32; off >= 1; off >>= 1) {
            r1 += __shfl_xor(r1, off);
            r2 += __shfl_xor(r2, off);
        }
        if (l == 0) {
            sc1[d] = r1 + sb1[0];
            sc2[d] = r2 + b12[0];
        }
    }
}

// ---------------- fused pooling + folded head (one block per graph) -------
__global__ __launch_bounds__(512) void pool_head(const float* __restrict__ feat,
                                                 const float* __restrict__ sc1,
                                                 const float* __restrict__ sc2,
                                                 const float* __restrict__ Wc,
                                                 const float* __restrict__ bc,
                                                 const float* __restrict__ c2w,
                                                 const float* __restrict__ c2b,
                                                 float* __restrict__ out) {
    __shared__ float s[NPG];
    __shared__ unsigned char keep[NPG];
    __shared__ float vbuf[8][CC];
    __shared__ float v0[CC];
    __shared__ float part[8][64];
    __shared__ float v2[64];
    const int g = blockIdx.x;
    const int i = threadIdx.x;

    float my = sc1[g * NPG + i];
    s[i] = my;
    __syncthreads();
    int rank = 0;
    for (int j = 0; j < NPG; ++j) {
        float sj = s[j];
        rank += (sj > my) || (sj == my && j < i);
    }
    int k1 = rank < KP1;
    __syncthreads();
    float my2 = k1 ? sc2[g * NPG + i] : -INFINITY;
    s[i] = my2;
    __syncthreads();
    rank = 0;
    for (int j = 0; j < NPG; ++j) {
        float sj = s[j];
        rank += (sj > my2) || (sj == my2 && j < i);
    }
    keep[i] = (unsigned char)(k1 && rank < KP2);
    __syncthreads();

    const int r = i >> 6, c4 = i & 63;
    float4 acc = make_float4(0.0f, 0.0f, 0.0f, 0.0f);
    const float4* f4 = (const float4*)(feat + (size_t)g * NPG * CC);
    for (int j = r; j < NPG; j += 8) {
        if (keep[j]) {
            float4 v = f4[j * 64 + c4];
            acc.x += v.x; acc.y += v.y; acc.z += v.z; acc.w += v.w;
        }
    }
    vbuf[r][c4 * 4 + 0] = acc.x;
    vbuf[r][c4 * 4 + 1] = acc.y;
    vbuf[r][c4 * 4 + 2] = acc.z;
    vbuf[r][c4 * 4 + 3] = acc.w;
    __syncthreads();
    if (i < CC) {
        float t = 0.0f;
#pragma unroll
        for (int q = 0; q < 8; ++q) t += vbuf[q][i];
        v0[i] = t * (1.0f / KP2);
    }
    __syncthreads();

    {
        const int q = i >> 6, cth = i & 63;
        float p = 0.0f;
        for (int j = q * 32; j < q * 32 + 32; ++j)
            p = fmaf(v0[j], Wc[j * 64 + cth], p);
        part[q][cth] = p;
    }
    __syncthreads();
    if (i < 64) {
        float u = bc[i];
#pragma unroll
        for (int q = 0; q < 8; ++q) u += part[q][i];
        v2[i] = fmaxf(u, 0.0f);
    }
    __syncthreads();
    if (i < 2) {
        float o = c2b[i];
        for (int j = 0; j < 64; ++j) o = fmaf(v2[j], c2w[j * 2 + i], o);
        s[i] = o;
    }
    __syncthreads();
    if (i == 0) {
        float a = s[0], bq = s[1];
        float mx = fmaxf(a, bq);
        float lse = mx + logf(expf(a - mx) + expf(bq - mx));
        out[g * 2 + 0] = a - lse;
        out[g * 2 + 1] = bq - lse;
    }
}

// ---------------- launcher ----------------
extern "C" void kernel_launch(void* const* d_in, const int* in_sizes, int n_in,
                              void* d_out, int out_size, void* d_ws, size_t ws_size,
                              hipStream_t stream) {
    const float* x      = (const float*)d_in[0];
    const int*   ei     = (const int*)d_in[1];
    const int*   src    = ei;
    const int*   dst    = ei + EG;
    const float* W1     = (const float*)d_in[3];
    const float* a_src1 = (const float*)d_in[4];
    const float* a_dst1 = (const float*)d_in[5];
    const float* b1     = (const float*)d_in[6];
    const float* W2     = (const float*)d_in[7];
    const float* a_src2 = (const float*)d_in[8];
    const float* a_dst2 = (const float*)d_in[9];
    const float* b2     = (const float*)d_in[10];
    const float* p1_sw  = (const float*)d_in[11];
    const float* p1_sb  = (const float*)d_in[12];
    const float* p1_tw  = (const float*)d_in[13];
    const float* p1_tb  = (const float*)d_in[14];
    const float* p2_sw  = (const float*)d_in[15];
    const float* p2_sb  = (const float*)d_in[16];
    const float* p2_tw  = (const float*)d_in[17];
    const float* p2_tb  = (const float*)d_in[18];
    const float* c1w    = (const float*)d_in[19];
    const float* c1b    = (const float*)d_in[20];
    const float* c2w    = (const float*)d_in[21];
    const float* c2b    = (const float*)d_in[22];
    float* out = (float*)d_out;

    // workspace layout
    float* ws = (float*)d_ws;
    unsigned short* xhi = (unsigned short*)ws;          // NN*FIN ushorts
    unsigned short* xlo = xhi + (size_t)NN * FIN;       // NN*FIN
    float* z = ws + (size_t)NN * FIN;                   // NN*CC floats
    float* fregion = z + (size_t)NN * CC;               // NN*CC floats (32 MB)
    unsigned short* fhi = (unsigned short*)fregion;     //   phase 1: fhi/flo bf16
    unsigned short* flo = fhi + (size_t)NN * CC;
    float* featF = fregion;                             //   phase 2: fp32 feat (alias)
    float* wsp = fregion + (size_t)NN * CC;
    unsigned short* w1ph = (unsigned short*)wsp;        // 256*128 packed
    unsigned short* w1pl = w1ph + 256 * FIN;
    unsigned short* w2ph = w1pl + 256 * FIN;            // 256*256 packed
    unsigned short* w2pl = w2ph + 256 * CC;
    float* es  = (float*)(w2pl + 256 * CC);             // N*H
    float* ed  = es + NN * HH;
    int* cnt   = (int*)(ed + NN * HH);                  // N
    int* rowp  = cnt + NN;                              // N+1
    int* cur   = rowp + NN + 1;                         // N
    int* esrc  = cur + NN;                              // E
    float* sc1 = (float*)(esrc + EG);                   // N
    float* sc2 = sc1 + NN;
    float* w12 = sc2 + NN;                              // C
    float* b12 = w12 + CC;                              // 1 (padded 64)
    float* T   = b12 + 64;                              // 256*64
    float* Wc  = T + CC * 64;                           // 256*64
    float* bc2 = Wc + CC * 64;                          // 64
    float* bcv = bc2 + 64;                              // 64

    // ---- prep + conversions + CSR build ----
    prep<<<194, 256, 0, stream>>>(cnt, p1_tw, p2_sw, p1_tb, p2_sb, w12, b12,
                                  p2_tw, c1w, p2_tb, T, bc2);
    conv_split<<<(NN * FIN / 4 + 255) / 256, 256, 0, stream>>>(x, xhi, xlo, NN * FIN / 4);
    conv_wpack<<<48, 256, 0, stream>>>(W1, W2, w1ph, w1pl, w2ph, w2pl);
    csr_hist<<<(EG + 255) / 256, 256, 0, stream>>>(dst, cnt);
    csr_scan<<<1, 1024, 0, stream>>>(cnt, rowp, cur);
    csr_scatter<<<(EG + 255) / 256, 256, 0, stream>>>(src, dst, cur, esrc);
    fold_W<<<65, 256, 0, stream>>>(p1_tw, T, p1_tb, bc2, c1b, Wc, bcv);

    // ---- GAT layer 1 ----
    gemm_mfma_attn<<<NN / 32, 256, 0, stream>>>(xhi, xlo, w1ph, w1pl, z, FIN,
                                                a_src1, a_dst1, es, ed);
    gat_edge<<<NN / 4, 256, 0, stream>>>(z, rowp, esrc, es, ed, b1,
                                         nullptr, fhi, flo,
                                         nullptr, nullptr, nullptr, nullptr,
                                         nullptr, nullptr);

    // ---- GAT layer 2 ----
    gemm_mfma_attn<<<NN / 32, 256, 0, stream>>>(fhi, flo, w2ph, w2pl, z, CC,
                                                a_src2, a_dst2, es, ed);
    gat_edge<<<NN / 4, 256, 0, stream>>>(z, rowp, esrc, es, ed, b2,
                                         featF, nullptr, nullptr,
                                         p1_sw, p1_sb, w12, b12, sc1, sc2);

    // ---- fused pooling + folded head ----
    pool_head<<<BG, 512, 0, stream>>>(featF, sc1, sc2, Wc, bcv, c2w, c2b, out);
}

// Round 11
// 343.353 us; speedup vs baseline: 1.2129x; 1.0347x over previous
//
#include <hip/hip_runtime.h>
#include <hip/hip_bf16.h>
#include <math.h>

// ---------------- problem constants ----------------
constexpr int NN  = 32768;   // nodes
constexpr int BG  = 64;      // graphs
constexpr int NPG = 512;     // nodes per graph
constexpr int EG  = 524288;  // edges
constexpr int HH  = 4;       // heads
constexpr int FH  = 64;      // per-head dim
constexpr int CC  = 256;     // H*Fh
constexpr int FIN = 128;
constexpr int KP1 = 256;     // pool1 k
constexpr int KP2 = 128;     // pool2 k
constexpr int NS  = 4;       // register edge slots: fast path deg <= 64

typedef __attribute__((ext_vector_type(8))) short short8;  // 8 bf16 = 4 VGPRs
typedef __attribute__((ext_vector_type(4))) float f32x4;

__device__ inline float leaky02(float v) { return v > 0.0f ? v : 0.2f * v; }

__device__ inline unsigned short f2bf(float v) {
    __hip_bfloat16 h = __float2bfloat16(v);
    return *(unsigned short*)&h;
}
__device__ inline float bf2f(unsigned short u) {
    __hip_bfloat16 h;
    *(unsigned short*)&h = u;
    return __bfloat162float(h);
}
__device__ inline void split2(float v, unsigned short& hi, unsigned short& lo) {
    hi = f2bf(v);
    lo = f2bf(v - bf2f(hi));
}

// ---------------- split-precision conversion kernels ----------------------
__global__ __launch_bounds__(256) void conv_split(const float* __restrict__ X,
                                                  unsigned short* __restrict__ Hi,
                                                  unsigned short* __restrict__ Lo,
                                                  int n4) {
    int i = blockIdx.x * 256 + threadIdx.x;
    if (i >= n4) return;
    float4 v = ((const float4*)X)[i];
    ushort4 h, l;
    split2(v.x, h.x, l.x);
    split2(v.y, h.y, l.y);
    split2(v.z, h.z, l.z);
    split2(v.w, h.w, l.w);
    ((ushort4*)Hi)[i] = h;
    ((ushort4*)Lo)[i] = l;
}

// W1 [128x256], W2 [256x256] fp32 -> FRAGMENT-PACKED split bf16.
// Packed layout: [nt (16 cols)][kg (32 k)][lane l][j]:
//   n = nt*16 + (l&15), k = kg*32 + (l>>4)*8 + j
__global__ __launch_bounds__(256) void conv_wpack(const float* __restrict__ W1,
                                                  const float* __restrict__ W2,
                                                  unsigned short* __restrict__ w1ph,
                                                  unsigned short* __restrict__ w1pl,
                                                  unsigned short* __restrict__ w2ph,
                                                  unsigned short* __restrict__ w2pl) {
    int idx = blockIdx.x * 256 + threadIdx.x;      // 0 .. 12287
    if (idx < 4096) {                              // W1: 16 nt x 4 kg x 64 l
        const int nt = idx >> 8, rem = idx & 255;
        const int kg = rem >> 6, l = rem & 63;
        const int n = nt * 16 + (l & 15);
        const int kb = kg * 32 + (l >> 4) * 8;
        unsigned short h[8], lo[8];
#pragma unroll
        for (int j = 0; j < 8; ++j) split2(W1[(kb + j) * CC + n], h[j], lo[j]);
#pragma unroll
        for (int j = 0; j < 8; ++j) {
            w1ph[(size_t)idx * 8 + j] = h[j];
            w1pl[(size_t)idx * 8 + j] = lo[j];
        }
    } else if (idx < 12288) {                      // W2: 16 nt x 8 kg x 64 l
        const int i2 = idx - 4096;
        const int nt = i2 >> 9, rem = i2 & 511;
        const int kg = rem >> 6, l = rem & 63;
        const int n = nt * 16 + (l & 15);
        const int kb = kg * 32 + (l >> 4) * 8;
        unsigned short h[8], lo[8];
#pragma unroll
        for (int j = 0; j < 8; ++j) split2(W2[(kb + j) * CC + n], h[j], lo[j]);
#pragma unroll
        for (int j = 0; j < 8; ++j) {
            w2ph[(size_t)i2 * 8 + j] = h[j];
            w2pl[(size_t)i2 * 8 + j] = lo[j];
        }
    }
}

// ---------------- MFMA GEMM: C[M,256] = A[M,K]@B[K,256], split-bf16 -------
__global__ __launch_bounds__(256, 4) void gemm_mfma_attn(
        const unsigned short* __restrict__ Ahi, const unsigned short* __restrict__ Alo,
        const unsigned short* __restrict__ Bph, const unsigned short* __restrict__ Bpl,
        float* __restrict__ Cm, int K,
        const float* __restrict__ a_src, const float* __restrict__ a_dst,
        float* __restrict__ es, float* __restrict__ ed) {
    const int t = threadIdx.x;
    const int w = t >> 6;          // wave = col strip = head
    const int l = t & 63;
    const int bx   = blockIdx.x;               // 0..1023
    const int xcd  = bx & 7;
    const int slot = bx >> 3;                  // 0..127
    const int gph  = xcd + ((slot >> 4) << 3); // graph
    const int row0 = gph * NPG + ((slot & 15) << 5);
    const int m = l & 15;
    const int q = l >> 4;
    const int ncol0 = w * 64;
    const int KG = K >> 5;

    const unsigned short* aH0 = Ahi + (size_t)(row0 + m) * K + q * 8;
    const unsigned short* aL0 = Alo + (size_t)(row0 + m) * K + q * 8;
    const unsigned short* aH1 = aH0 + (size_t)16 * K;
    const unsigned short* aL1 = aL0 + (size_t)16 * K;

    f32x4 acc0[4], acc1[4];
#pragma unroll
    for (int c = 0; c < 4; ++c) {
        acc0[c] = (f32x4){0.f, 0.f, 0.f, 0.f};
        acc1[c] = (f32x4){0.f, 0.f, 0.f, 0.f};
    }

    for (int kg = 0; kg < KG; ++kg) {
        const int ko = kg * 32;
        short8 ah0 = *(const short8*)(aH0 + ko);
        short8 al0 = *(const short8*)(aL0 + ko);
        short8 ah1 = *(const short8*)(aH1 + ko);
        short8 al1 = *(const short8*)(aL1 + ko);
#pragma unroll
        for (int c = 0; c < 4; ++c) {
            const int nt = (w << 2) + c;
            const size_t boff = ((size_t)(nt * KG + kg) * 64 + l) * 8;
            short8 bh = *(const short8*)(Bph + boff);
            short8 bl = *(const short8*)(Bpl + boff);
            acc0[c] = __builtin_amdgcn_mfma_f32_16x16x32_bf16(ah0, bh, acc0[c], 0, 0, 0);
            acc0[c] = __builtin_amdgcn_mfma_f32_16x16x32_bf16(ah0, bl, acc0[c], 0, 0, 0);
            acc0[c] = __builtin_amdgcn_mfma_f32_16x16x32_bf16(al0, bh, acc0[c], 0, 0, 0);
            acc1[c] = __builtin_amdgcn_mfma_f32_16x16x32_bf16(ah1, bh, acc1[c], 0, 0, 0);
            acc1[c] = __builtin_amdgcn_mfma_f32_16x16x32_bf16(ah1, bl, acc1[c], 0, 0, 0);
            acc1[c] = __builtin_amdgcn_mfma_f32_16x16x32_bf16(al1, bh, acc1[c], 0, 0, 0);
        }
    }

#pragma unroll
    for (int c = 0; c < 4; ++c)
#pragma unroll
        for (int r = 0; r < 4; ++r) {
            Cm[(size_t)(row0 + q * 4 + r) * CC + ncol0 + c * 16 + m] = acc0[c][r];
            Cm[(size_t)(row0 + 16 + q * 4 + r) * CC + ncol0 + c * 16 + m] = acc1[c][r];
        }

    float asv[4], adv[4];
#pragma unroll
    for (int c = 0; c < 4; ++c) {
        asv[c] = a_src[ncol0 + c * 16 + m];
        adv[c] = a_dst[ncol0 + c * 16 + m];
    }
#pragma unroll
    for (int r = 0; r < 4; ++r) {
        float ps0 = 0.f, pd0 = 0.f, ps1 = 0.f, pd1 = 0.f;
#pragma unroll
        for (int c = 0; c < 4; ++c) {
            ps0 = fmaf(acc0[c][r], asv[c], ps0);
            pd0 = fmaf(acc0[c][r], adv[c], pd0);
            ps1 = fmaf(acc1[c][r], asv[c], ps1);
            pd1 = fmaf(acc1[c][r], adv[c], pd1);
        }
#pragma unroll
        for (int o = 8; o >= 1; o >>= 1) {
            ps0 += __shfl_down(ps0, o, 16);
            pd0 += __shfl_down(pd0, o, 16);
            ps1 += __shfl_down(ps1, o, 16);
            pd1 += __shfl_down(pd1, o, 16);
        }
        if (m == 0) {
            es[(row0 + q * 4 + r) * HH + w] = ps0;
            ed[(row0 + q * 4 + r) * HH + w] = pd0;
            es[(row0 + 16 + q * 4 + r) * HH + w] = ps1;
            ed[(row0 + 16 + q * 4 + r) * HH + w] = pd1;
        }
    }
}

// ---------------- prep: zero cnt + w12 + T = tw2@c1w + bc2 = tb2@c1w -------
__global__ __launch_bounds__(256) void prep(int* __restrict__ cnt,
                                            const float* __restrict__ tw1,
                                            const float* __restrict__ sw2,
                                            const float* __restrict__ tb1,
                                            const float* __restrict__ sb2,
                                            float* __restrict__ w12,
                                            float* __restrict__ b12,
                                            const float* __restrict__ tw2,
                                            const float* __restrict__ c1w,
                                            const float* __restrict__ tb2,
                                            float* __restrict__ T,
                                            float* __restrict__ bc2) {
    const int b = blockIdx.x;
    const int t = threadIdx.x;
    if (b < 128) {
        cnt[b * 256 + t] = 0;
    } else if (b == 128) {
        float s = 0.0f;
        for (int o = 0; o < CC; ++o) s += tw1[t * CC + o] * sw2[o];
        w12[t] = s;
        if (t == 0) {
            float bb = 0.0f;
            for (int o = 0; o < CC; ++o) bb += tb1[o] * sw2[o];
            *b12 = bb + sb2[0];
        }
    } else if (b < 193) {
        const int r = (b - 129) * 4 + (t >> 6);
        const int cth = t & 63;
        float s = 0.0f;
        for (int j = 0; j < CC; ++j) s = fmaf(tw2[r * CC + j], c1w[j * 64 + cth], s);
        T[r * 64 + cth] = s;
    } else if (t < 64) {
        float s = 0.0f;
        for (int j = 0; j < CC; ++j) s = fmaf(tb2[j], c1w[j * 64 + t], s);
        bc2[t] = s;
    }
}

// ---------------- fold_W: Wc = tw1@T, bc = tb1@T + bc2 + c1b --------------
__global__ __launch_bounds__(256) void fold_W(const float* __restrict__ tw1,
                                              const float* __restrict__ T,
                                              const float* __restrict__ tb1,
                                              const float* __restrict__ bc2,
                                              const float* __restrict__ c1b,
                                              float* __restrict__ Wc,
                                              float* __restrict__ bc) {
    const int b = blockIdx.x;
    const int t = threadIdx.x;
    if (b < 64) {
        const int r = b * 4 + (t >> 6);
        const int cth = t & 63;
        float s = 0.0f;
        for (int j = 0; j < CC; ++j) s = fmaf(tw1[r * CC + j], T[j * 64 + cth], s);
        Wc[r * 64 + cth] = s;
    } else if (t < 64) {
        float s = 0.0f;
        for (int j = 0; j < CC; ++j) s = fmaf(tb1[j], T[j * 64 + t], s);
        bc[t] = s + bc2[t] + c1b[t];
    }
}

// ---------------- CSR build (by dst) ----------------
__global__ void csr_hist(const int* __restrict__ dst, int* cnt) {
    int e = blockIdx.x * 256 + threadIdx.x;
    if (e < EG) atomicAdd(&cnt[dst[e]], 1);
}
__global__ __launch_bounds__(1024) void csr_scan(const int* __restrict__ cnt,
                                                 int* __restrict__ rowp,
                                                 int* __restrict__ cur) {
    __shared__ int tmp[1024];
    const int t = threadIdx.x;
    const int base = t * 32;
    int local[32];
    int s = 0;
#pragma unroll
    for (int i = 0; i < 32; ++i) { local[i] = s; s += cnt[base + i]; }
    tmp[t] = s;
    __syncthreads();
    for (int o = 1; o < 1024; o <<= 1) {
        int v = (t >= o) ? tmp[t - o] : 0;
        __syncthreads();
        tmp[t] += v;
        __syncthreads();
    }
    int off = tmp[t] - s;  // exclusive prefix
#pragma unroll
    for (int i = 0; i < 32; ++i) {
        int p = off + local[i];
        rowp[base + i] = p;
        cur[base + i] = p;
    }
    if (t == 1023) rowp[NN] = off + s;
}
__global__ void csr_scatter(const int* __restrict__ src, const int* __restrict__ dst,
                            int* cur, int* __restrict__ esrc) {
    int e = blockIdx.x * 256 + threadIdx.x;
    if (e < EG) {
        int p = atomicAdd(&cur[dst[e]], 1);
        esrc[p] = src[e];
    }
}

// ---------------- fused GAT edge stage: softmax + aggregate + ELU ----------
// One wave per dst node, no barriers, XCD-swizzled.
// Phase B v2: alpha zero-padded, 8-edge fully-unrolled blocks -> 8 gathers
// in flight; srcn via readlane (SGPR base -> scalar addressing on the load).
__global__ __launch_bounds__(256) void gat_edge(const float* __restrict__ z,
                                                const int* __restrict__ rowp,
                                                const int* __restrict__ esrc,
                                                const float* __restrict__ es,
                                                const float* __restrict__ ed,
                                                const float* __restrict__ bias,
                                                float* __restrict__ out,
                                                unsigned short* __restrict__ outh,
                                                unsigned short* __restrict__ outl,
                                                const float* __restrict__ sw1,
                                                const float* __restrict__ sb1,
                                                const float* __restrict__ w12,
                                                const float* __restrict__ b12,
                                                float* __restrict__ sc1,
                                                float* __restrict__ sc2) {
    const int w = threadIdx.x >> 6;
    const int l = threadIdx.x & 63;
    const int b    = blockIdx.x;              // 0..8191
    const int xcd  = b & 7;
    const int slot = b >> 3;                  // 0..1023
    const int gph  = xcd + ((slot >> 7) << 3);
    const int d    = gph * NPG + ((slot & 127) << 2) + w;

    const int h  = l & 3;
    const int ei = l >> 2;
    const int h2 = l >> 4;
    const int beg = rowp[d];
    const int deg = rowp[d + 1] - beg;

    const float4 zv = *(const float4*)(z + (size_t)d * CC + 4 * l);
    float4 acc;

    if (deg <= 16 * NS) {
        // ---- phase A: register softmax (alpha zero-padded to slot grid) ----
        const float edh = ed[d * HH + h];
        int   sidx[NS];
        float v[NS];
#pragma unroll
        for (int j = 0; j < NS; ++j) { sidx[j] = d; v[j] = 0.0f; }
        float vmax = -INFINITY, eself = 0.0f;
        float vself = 0.0f;
        if (ei == 0) {
            vself = leaky02(es[d * HH + h] + edh);
            vmax = vself;
        }
#pragma unroll
        for (int j = 0; j < NS; ++j) {
            int i = ei + 16 * j;
            if (i < deg) {
                sidx[j] = esrc[beg + i];
                v[j] = leaky02(es[sidx[j] * HH + h] + edh);
                vmax = fmaxf(vmax, v[j]);
            }
        }
#pragma unroll
        for (int o = 4; o <= 32; o <<= 1) vmax = fmaxf(vmax, __shfl_xor(vmax, o));
        float dsum = 0.0f;
#pragma unroll
        for (int j = 0; j < NS; ++j) {
            int i = ei + 16 * j;
            if (i < deg) { v[j] = __expf(v[j] - vmax); dsum += v[j]; }
        }
        if (ei == 0) { eself = __expf(vself - vmax); dsum += eself; }
#pragma unroll
        for (int o = 4; o <= 32; o <<= 1) dsum += __shfl_xor(dsum, o);
        const float inv = 1.0f / (dsum + 1e-16f);
#pragma unroll
        for (int j = 0; j < NS; ++j) v[j] *= inv;   // normalized alpha (0 = pad)
        eself *= inv;

        // ---- phase B: fully-unrolled 8-edge blocks, pipelined gathers ----
        float aself = __shfl(eself, h2);
        acc = make_float4(aself * zv.x, aself * zv.y, aself * zv.z, aself * zv.w);
#pragma unroll
        for (int jj = 0; jj < 2 * NS; ++jj) {
            if (8 * jj < deg) {
                const int j = jj >> 1;
                const int lb = 32 * (jj & 1);
#pragma unroll
                for (int s = 0; s < 8; ++s) {
                    int   srcn = __builtin_amdgcn_readlane(sidx[j], lb + 4 * s);
                    float a    = __shfl(v[j], lb + 4 * s + h2);
                    const float4 zs = *(const float4*)(z + (size_t)srcn * CC + 4 * l);
                    acc.x = fmaf(a, zs.x, acc.x);
                    acc.y = fmaf(a, zs.y, acc.y);
                    acc.z = fmaf(a, zs.z, acc.z);
                    acc.w = fmaf(a, zs.w, acc.w);
                }
            }
        }
    } else {
        // ---- generic slow path (never taken for the fixed input) ----
        const float edh = ed[d * HH + h];
        float vmax = (ei == 0) ? leaky02(es[d * HH + h] + edh) : -INFINITY;
        for (int i = ei; i < deg; i += 16)
            vmax = fmaxf(vmax, leaky02(es[esrc[beg + i] * HH + h] + edh));
#pragma unroll
        for (int o = 4; o <= 32; o <<= 1) vmax = fmaxf(vmax, __shfl_xor(vmax, o));
        float dsum = (ei == 0) ? __expf(leaky02(es[d * HH + h] + edh) - vmax) : 0.0f;
        for (int i = ei; i < deg; i += 16)
            dsum += __expf(leaky02(es[esrc[beg + i] * HH + h] + edh) - vmax);
#pragma unroll
        for (int o = 4; o <= 32; o <<= 1) dsum += __shfl_xor(dsum, o);
        const float inv = 1.0f / (dsum + 1e-16f);

        const float vmaxc = __shfl(vmax, h2);
        const float invc  = __shfl(inv,  h2);
        const float edh4  = ed[d * HH + h2];
        float a0 = __expf(leaky02(es[d * HH + h2] + edh4) - vmaxc) * invc;
        acc = make_float4(a0 * zv.x, a0 * zv.y, a0 * zv.z, a0 * zv.w);
        for (int i = 0; i < deg; ++i) {
            int srcn = esrc[beg + i];
            float a = __expf(leaky02(es[srcn * HH + h2] + edh4) - vmaxc) * invc;
            float4 zs = *(const float4*)(z + (size_t)srcn * CC + 4 * l);
            acc.x = fmaf(a, zs.x, acc.x);
            acc.y = fmaf(a, zs.y, acc.y);
            acc.z = fmaf(a, zs.z, acc.z);
            acc.w = fmaf(a, zs.w, acc.w);
        }
    }

    // ---- epilogue: bias + ELU ----
    const float4 bv = *(const float4*)(bias + 4 * l);
    float4 o;
    o.x = acc.x + bv.x; o.x = o.x > 0.0f ? o.x : expm1f(o.x);
    o.y = acc.y + bv.y; o.y = o.y > 0.0f ? o.y : expm1f(o.y);
    o.z = acc.z + bv.z; o.z = o.z > 0.0f ? o.z : expm1f(o.z);
    o.w = acc.w + bv.w; o.w = o.w > 0.0f ? o.w : expm1f(o.w);

    if (out) *(float4*)(out + (size_t)d * CC + 4 * l) = o;
    if (outh) {   // bf16 split write (feeds next layer's MFMA GEMM)
        ushort4 uh, ul;
        split2(o.x, uh.x, ul.x);
        split2(o.y, uh.y, ul.y);
        split2(o.z, uh.z, ul.z);
        split2(o.w, uh.w, ul.w);
        ((ushort4*)outh)[(size_t)d * 64 + l] = uh;
        ((ushort4*)outl)[(size_t)d * 64 + l] = ul;
    }

    if (sc1) {
        const float4 s1 = *(const float4*)(sw1 + 4 * l);
        const float4 s2 = *(const float4*)(w12 + 4 * l);
        float r1 = o.x * s1.x + o.y * s1.y + o.z * s1.z + o.w * s1.w;
        float r2 = o.x * s2.x + o.y * s2.y + o.z * s2.z + o.w * s2.w;
#pragma unroll
        for (int off = 32; off >= 1; off >>= 1) {
            r1 += __shfl_xor(r1, off);
            r2 += __shfl_xor(r2, off);
        }
        if (l == 0) {
            sc1[d] = r1 + sb1[0];
            sc2[d] = r2 + b12[0];
        }
    }
}

// ---------------- fused pooling + folded head (one block per graph) -------
__global__ __launch_bounds__(512) void pool_head(const float* __restrict__ feat,
                                                 const float* __restrict__ sc1,
                                                 const float* __restrict__ sc2,
                                                 const float* __restrict__ Wc,
                                                 const float* __restrict__ bc,
                                                 const float* __restrict__ c2w,
                                                 const float* __restrict__ c2b,
                                                 float* __restrict__ out) {
    __shared__ float s[NPG];
    __shared__ unsigned char keep[NPG];
    __shared__ float vbuf[8][CC];
    __shared__ float v0[CC];
    __shared__ float part[8][64];
    __shared__ float v2[64];
    const int g = blockIdx.x;
    const int i = threadIdx.x;

    float my = sc1[g * NPG + i];
    s[i] = my;
    __syncthreads();
    int rank = 0;
    for (int j = 0; j < NPG; ++j) {
        float sj = s[j];
        rank += (sj > my) || (sj == my && j < i);
    }
    int k1 = rank < KP1;
    __syncthreads();
    float my2 = k1 ? sc2[g * NPG + i] : -INFINITY;
    s[i] = my2;
    __syncthreads();
    rank = 0;
    for (int j = 0; j < NPG; ++j) {
        float sj = s[j];
        rank += (sj > my2) || (sj == my2 && j < i);
    }
    keep[i] = (unsigned char)(k1 && rank < KP2);
    __syncthreads();

    const int r = i >> 6, c4 = i & 63;
    float4 acc = make_float4(0.0f, 0.0f, 0.0f, 0.0f);
    const float4* f4 = (const float4*)(feat + (size_t)g * NPG * CC);
    for (int j = r; j < NPG; j += 8) {
        if (keep[j]) {
            float4 v = f4[j * 64 + c4];
            acc.x += v.x; acc.y += v.y; acc.z += v.z; acc.w += v.w;
        }
    }
    vbuf[r][c4 * 4 + 0] = acc.x;
    vbuf[r][c4 * 4 + 1] = acc.y;
    vbuf[r][c4 * 4 + 2] = acc.z;
    vbuf[r][c4 * 4 + 3] = acc.w;
    __syncthreads();
    if (i < CC) {
        float t = 0.0f;
#pragma unroll
        for (int q = 0; q < 8; ++q) t += vbuf[q][i];
        v0[i] = t * (1.0f / KP2);
    }
    __syncthreads();

    {
        const int q = i >> 6, cth = i & 63;
        float p = 0.0f;
        for (int j = q * 32; j < q * 32 + 32; ++j)
            p = fmaf(v0[j], Wc[j * 64 + cth], p);
        part[q][cth] = p;
    }
    __syncthreads();
    if (i < 64) {
        float u = bc[i];
#pragma unroll
        for (int q = 0; q < 8; ++q) u += part[q][i];
        v2[i] = fmaxf(u, 0.0f);
    }
    __syncthreads();
    if (i < 2) {
        float o = c2b[i];
        for (int j = 0; j < 64; ++j) o = fmaf(v2[j], c2w[j * 2 + i], o);
        s[i] = o;
    }
    __syncthreads();
    if (i == 0) {
        float a = s[0], bq = s[1];
        float mx = fmaxf(a, bq);
        float lse = mx + logf(expf(a - mx) + expf(bq - mx));
        out[g * 2 + 0] = a - lse;
        out[g * 2 + 1] = bq - lse;
    }
}

// ---------------- launcher ----------------
extern "C" void kernel_launch(void* const* d_in, const int* in_sizes, int n_in,
                              void* d_out, int out_size, void* d_ws, size_t ws_size,
                              hipStream_t stream) {
    const float* x      = (const float*)d_in[0];
    const int*   ei     = (const int*)d_in[1];
    const int*   src    = ei;
    const int*   dst    = ei + EG;
    const float* W1     = (const float*)d_in[3];
    const float* a_src1 = (const float*)d_in[4];
    const float* a_dst1 = (const float*)d_in[5];
    const float* b1     = (const float*)d_in[6];
    const float* W2     = (const float*)d_in[7];
    const float* a_src2 = (const float*)d_in[8];
    const float* a_dst2 = (const float*)d_in[9];
    const float* b2     = (const float*)d_in[10];
    const float* p1_sw  = (const float*)d_in[11];
    const float* p1_sb  = (const float*)d_in[12];
    const float* p1_tw  = (const float*)d_in[13];
    const float* p1_tb  = (const float*)d_in[14];
    const float* p2_sw  = (const float*)d_in[15];
    const float* p2_sb  = (const float*)d_in[16];
    const float* p2_tw  = (const float*)d_in[17];
    const float* p2_tb  = (const float*)d_in[18];
    const float* c1w    = (const float*)d_in[19];
    const float* c1b    = (const float*)d_in[20];
    const float* c2w    = (const float*)d_in[21];
    const float* c2b    = (const float*)d_in[22];
    float* out = (float*)d_out;

    // workspace layout
    float* ws = (float*)d_ws;
    unsigned short* xhi = (unsigned short*)ws;          // NN*FIN ushorts
    unsigned short* xlo = xhi + (size_t)NN * FIN;       // NN*FIN
    float* z = ws + (size_t)NN * FIN;                   // NN*CC floats
    float* fregion = z + (size_t)NN * CC;               // NN*CC floats (32 MB)
    unsigned short* fhi = (unsigned short*)fregion;     //   phase 1: fhi/flo bf16
    unsigned short* flo = fhi + (size_t)NN * CC;
    float* featF = fregion;                             //   phase 2: fp32 feat (alias)
    float* wsp = fregion + (size_t)NN * CC;
    unsigned short* w1ph = (unsigned short*)wsp;        // 256*128 packed
    unsigned short* w1pl = w1ph + 256 * FIN;
    unsigned short* w2ph = w1pl + 256 * FIN;            // 256*256 packed
    unsigned short* w2pl = w2ph + 256 * CC;
    float* es  = (float*)(w2pl + 256 * CC);             // N*H
    float* ed  = es + NN * HH;
    int* cnt   = (int*)(ed + NN * HH);                  // N
    int* rowp  = cnt + NN;                              // N+1
    int* cur   = rowp + NN + 1;                         // N
    int* esrc  = cur + NN;                              // E
    float* sc1 = (float*)(esrc + EG);                   // N
    float* sc2 = sc1 + NN;
    float* w12 = sc2 + NN;                              // C
    float* b12 = w12 + CC;                              // 1 (padded 64)
    float* T   = b12 + 64;                              // 256*64
    float* Wc  = T + CC * 64;                           // 256*64
    float* bc2 = Wc + CC * 64;                          // 64
    float* bcv = bc2 + 64;                              // 64

    // ---- prep + conversions + CSR build ----
    prep<<<194, 256, 0, stream>>>(cnt, p1_tw, p2_sw, p1_tb, p2_sb, w12, b12,
                                  p2_tw, c1w, p2_tb, T, bc2);
    conv_split<<<(NN * FIN / 4 + 255) / 256, 256, 0, stream>>>(x, xhi, xlo, NN * FIN / 4);
    conv_wpack<<<48, 256, 0, stream>>>(W1, W2, w1ph, w1pl, w2ph, w2pl);
    csr_hist<<<(EG + 255) / 256, 256, 0, stream>>>(dst, cnt);
    csr_scan<<<1, 1024, 0, stream>>>(cnt, rowp, cur);
    csr_scatter<<<(EG + 255) / 256, 256, 0, stream>>>(src, dst, cur, esrc);
    fold_W<<<65, 256, 0, stream>>>(p1_tw, T, p1_tb, bc2, c1b, Wc, bcv);

    // ---- GAT layer 1 ----
    gemm_mfma_attn<<<NN / 32, 256, 0, stream>>>(xhi, xlo, w1ph, w1pl, z, FIN,
                                                a_src1, a_dst1, es, ed);
    gat_edge<<<NN / 4, 256, 0, stream>>>(z, rowp, esrc, es, ed, b1,
                                         nullptr, fhi, flo,
                                         nullptr, nullptr, nullptr, nullptr,
                                         nullptr, nullptr);

    // ---- GAT layer 2 ----
    gemm_mfma_attn<<<NN / 32, 256, 0, stream>>>(fhi, flo, w2ph, w2pl, z, CC,
                                                a_src2, a_dst2, es, ed);
    gat_edge<<<NN / 4, 256, 0, stream>>>(z, rowp, esrc, es, ed, b2,
                                         featF, nullptr, nullptr,
                                         p1_sw, p1_sb, w12, b12, sc1, sc2);

    // ---- fused pooling + folded head ----
    pool_head<<<BG, 512, 0, stream>>>(featF, sc1, sc2, Wc, bcv, c2w, c2b, out);
}

// Round 12
// 340.290 us; speedup vs baseline: 1.2238x; 1.0090x over previous
//
#include <hip/hip_runtime.h>
#include <hip/hip_bf16.h>
#include <math.h>

// ---------------- problem constants ----------------
constexpr int NN  = 32768;   // nodes
constexpr int BG  = 64;      // graphs
constexpr int NPG = 512;     // nodes per graph
constexpr int EG  = 524288;  // edges
constexpr int HH  = 4;       // heads
constexpr int FH  = 64;      // per-head dim
constexpr int CC  = 256;     // H*Fh
constexpr int FIN = 128;
constexpr int KP1 = 256;     // pool1 k
constexpr int KP2 = 128;     // pool2 k
constexpr int NS  = 4;       // register edge slots: fast path deg <= 64

typedef __attribute__((ext_vector_type(8))) short short8;  // 8 bf16 = 4 VGPRs
typedef __attribute__((ext_vector_type(4))) float f32x4;

__device__ inline float leaky02(float v) { return v > 0.0f ? v : 0.2f * v; }

__device__ inline unsigned short f2bf(float v) {
    __hip_bfloat16 h = __float2bfloat16(v);
    return *(unsigned short*)&h;
}
__device__ inline float bf2f(unsigned short u) {
    __hip_bfloat16 h;
    *(unsigned short*)&h = u;
    return __bfloat162float(h);
}
__device__ inline void split2(float v, unsigned short& hi, unsigned short& lo) {
    hi = f2bf(v);
    lo = f2bf(v - bf2f(hi));
}

// ---------------- split-precision conversion kernels ----------------------
__global__ __launch_bounds__(256) void conv_split(const float* __restrict__ X,
                                                  unsigned short* __restrict__ Hi,
                                                  unsigned short* __restrict__ Lo,
                                                  int n4) {
    int i = blockIdx.x * 256 + threadIdx.x;
    if (i >= n4) return;
    float4 v = ((const float4*)X)[i];
    ushort4 h, l;
    split2(v.x, h.x, l.x);
    split2(v.y, h.y, l.y);
    split2(v.z, h.z, l.z);
    split2(v.w, h.w, l.w);
    ((ushort4*)Hi)[i] = h;
    ((ushort4*)Lo)[i] = l;
}

// W1 [128x256], W2 [256x256] fp32 -> FRAGMENT-PACKED split bf16.
// Packed layout: [nt (16 cols)][kg (32 k)][lane l][j]:
//   n = nt*16 + (l&15), k = kg*32 + (l>>4)*8 + j
__global__ __launch_bounds__(256) void conv_wpack(const float* __restrict__ W1,
                                                  const float* __restrict__ W2,
                                                  unsigned short* __restrict__ w1ph,
                                                  unsigned short* __restrict__ w1pl,
                                                  unsigned short* __restrict__ w2ph,
                                                  unsigned short* __restrict__ w2pl) {
    int idx = blockIdx.x * 256 + threadIdx.x;      // 0 .. 12287
    if (idx < 4096) {                              // W1: 16 nt x 4 kg x 64 l
        const int nt = idx >> 8, rem = idx & 255;
        const int kg = rem >> 6, l = rem & 63;
        const int n = nt * 16 + (l & 15);
        const int kb = kg * 32 + (l >> 4) * 8;
        unsigned short h[8], lo[8];
#pragma unroll
        for (int j = 0; j < 8; ++j) split2(W1[(kb + j) * CC + n], h[j], lo[j]);
#pragma unroll
        for (int j = 0; j < 8; ++j) {
            w1ph[(size_t)idx * 8 + j] = h[j];
            w1pl[(size_t)idx * 8 + j] = lo[j];
        }
    } else if (idx < 12288) {                      // W2: 16 nt x 8 kg x 64 l
        const int i2 = idx - 4096;
        const int nt = i2 >> 9, rem = i2 & 511;
        const int kg = rem >> 6, l = rem & 63;
        const int n = nt * 16 + (l & 15);
        const int kb = kg * 32 + (l >> 4) * 8;
        unsigned short h[8], lo[8];
#pragma unroll
        for (int j = 0; j < 8; ++j) split2(W2[(kb + j) * CC + n], h[j], lo[j]);
#pragma unroll
        for (int j = 0; j < 8; ++j) {
            w2ph[(size_t)i2 * 8 + j] = h[j];
            w2pl[(size_t)i2 * 8 + j] = lo[j];
        }
    }
}

// ---------------- MFMA GEMM: C[M,256] = A[M,K]@B[K,256], split-bf16 -------
__global__ __launch_bounds__(256, 4) void gemm_mfma_attn(
        const unsigned short* __restrict__ Ahi, const unsigned short* __restrict__ Alo,
        const unsigned short* __restrict__ Bph, const unsigned short* __restrict__ Bpl,
        float* __restrict__ Cm, int K,
        const float* __restrict__ a_src, const float* __restrict__ a_dst,
        float* __restrict__ es, float* __restrict__ ed) {
    const int t = threadIdx.x;
    const int w = t >> 6;          // wave = col strip = head
    const int l = t & 63;
    const int bx   = blockIdx.x;               // 0..1023
    const int xcd  = bx & 7;
    const int slot = bx >> 3;                  // 0..127
    const int gph  = xcd + ((slot >> 4) << 3); // graph
    const int row0 = gph * NPG + ((slot & 15) << 5);
    const int m = l & 15;
    const int q = l >> 4;
    const int ncol0 = w * 64;
    const int KG = K >> 5;

    const unsigned short* aH0 = Ahi + (size_t)(row0 + m) * K + q * 8;
    const unsigned short* aL0 = Alo + (size_t)(row0 + m) * K + q * 8;
    const unsigned short* aH1 = aH0 + (size_t)16 * K;
    const unsigned short* aL1 = aL0 + (size_t)16 * K;

    f32x4 acc0[4], acc1[4];
#pragma unroll
    for (int c = 0; c < 4; ++c) {
        acc0[c] = (f32x4){0.f, 0.f, 0.f, 0.f};
        acc1[c] = (f32x4){0.f, 0.f, 0.f, 0.f};
    }

    for (int kg = 0; kg < KG; ++kg) {
        const int ko = kg * 32;
        short8 ah0 = *(const short8*)(aH0 + ko);
        short8 al0 = *(const short8*)(aL0 + ko);
        short8 ah1 = *(const short8*)(aH1 + ko);
        short8 al1 = *(const short8*)(aL1 + ko);
#pragma unroll
        for (int c = 0; c < 4; ++c) {
            const int nt = (w << 2) + c;
            const size_t boff = ((size_t)(nt * KG + kg) * 64 + l) * 8;
            short8 bh = *(const short8*)(Bph + boff);
            short8 bl = *(const short8*)(Bpl + boff);
            acc0[c] = __builtin_amdgcn_mfma_f32_16x16x32_bf16(ah0, bh, acc0[c], 0, 0, 0);
            acc0[c] = __builtin_amdgcn_mfma_f32_16x16x32_bf16(ah0, bl, acc0[c], 0, 0, 0);
            acc0[c] = __builtin_amdgcn_mfma_f32_16x16x32_bf16(al0, bh, acc0[c], 0, 0, 0);
            acc1[c] = __builtin_amdgcn_mfma_f32_16x16x32_bf16(ah1, bh, acc1[c], 0, 0, 0);
            acc1[c] = __builtin_amdgcn_mfma_f32_16x16x32_bf16(ah1, bl, acc1[c], 0, 0, 0);
            acc1[c] = __builtin_amdgcn_mfma_f32_16x16x32_bf16(al1, bh, acc1[c], 0, 0, 0);
        }
    }

#pragma unroll
    for (int c = 0; c < 4; ++c)
#pragma unroll
        for (int r = 0; r < 4; ++r) {
            Cm[(size_t)(row0 + q * 4 + r) * CC + ncol0 + c * 16 + m] = acc0[c][r];
            Cm[(size_t)(row0 + 16 + q * 4 + r) * CC + ncol0 + c * 16 + m] = acc1[c][r];
        }

    float asv[4], adv[4];
#pragma unroll
    for (int c = 0; c < 4; ++c) {
        asv[c] = a_src[ncol0 + c * 16 + m];
        adv[c] = a_dst[ncol0 + c * 16 + m];
    }
#pragma unroll
    for (int r = 0; r < 4; ++r) {
        float ps0 = 0.f, pd0 = 0.f, ps1 = 0.f, pd1 = 0.f;
#pragma unroll
        for (int c = 0; c < 4; ++c) {
            ps0 = fmaf(acc0[c][r], asv[c], ps0);
            pd0 = fmaf(acc0[c][r], adv[c], pd0);
            ps1 = fmaf(acc1[c][r], asv[c], ps1);
            pd1 = fmaf(acc1[c][r], adv[c], pd1);
        }
#pragma unroll
        for (int o = 8; o >= 1; o >>= 1) {
            ps0 += __shfl_down(ps0, o, 16);
            pd0 += __shfl_down(pd0, o, 16);
            ps1 += __shfl_down(ps1, o, 16);
            pd1 += __shfl_down(pd1, o, 16);
        }
        if (m == 0) {
            es[(row0 + q * 4 + r) * HH + w] = ps0;
            ed[(row0 + q * 4 + r) * HH + w] = pd0;
            es[(row0 + 16 + q * 4 + r) * HH + w] = ps1;
            ed[(row0 + 16 + q * 4 + r) * HH + w] = pd1;
        }
    }
}

// ---------------- prep: zero cnt + w12 + T = tw2@c1w + bc2 = tb2@c1w -------
__global__ __launch_bounds__(256) void prep(int* __restrict__ cnt,
                                            const float* __restrict__ tw1,
                                            const float* __restrict__ sw2,
                                            const float* __restrict__ tb1,
                                            const float* __restrict__ sb2,
                                            float* __restrict__ w12,
                                            float* __restrict__ b12,
                                            const float* __restrict__ tw2,
                                            const float* __restrict__ c1w,
                                            const float* __restrict__ tb2,
                                            float* __restrict__ T,
                                            float* __restrict__ bc2) {
    const int b = blockIdx.x;
    const int t = threadIdx.x;
    if (b < 128) {
        cnt[b * 256 + t] = 0;
    } else if (b == 128) {
        float s = 0.0f;
        for (int o = 0; o < CC; ++o) s += tw1[t * CC + o] * sw2[o];
        w12[t] = s;
        if (t == 0) {
            float bb = 0.0f;
            for (int o = 0; o < CC; ++o) bb += tb1[o] * sw2[o];
            *b12 = bb + sb2[0];
        }
    } else if (b < 193) {
        const int r = (b - 129) * 4 + (t >> 6);
        const int cth = t & 63;
        float s = 0.0f;
        for (int j = 0; j < CC; ++j) s = fmaf(tw2[r * CC + j], c1w[j * 64 + cth], s);
        T[r * 64 + cth] = s;
    } else if (t < 64) {
        float s = 0.0f;
        for (int j = 0; j < CC; ++j) s = fmaf(tb2[j], c1w[j * 64 + t], s);
        bc2[t] = s;
    }
}

// ---------------- fold_W: Wc = tw1@T, bc = tb1@T + bc2 + c1b --------------
__global__ __launch_bounds__(256) void fold_W(const float* __restrict__ tw1,
                                              const float* __restrict__ T,
                                              const float* __restrict__ tb1,
                                              const float* __restrict__ bc2,
                                              const float* __restrict__ c1b,
                                              float* __restrict__ Wc,
                                              float* __restrict__ bc) {
    const int b = blockIdx.x;
    const int t = threadIdx.x;
    if (b < 64) {
        const int r = b * 4 + (t >> 6);
        const int cth = t & 63;
        float s = 0.0f;
        for (int j = 0; j < CC; ++j) s = fmaf(tw1[r * CC + j], T[j * 64 + cth], s);
        Wc[r * 64 + cth] = s;
    } else if (t < 64) {
        float s = 0.0f;
        for (int j = 0; j < CC; ++j) s = fmaf(tb1[j], T[j * 64 + t], s);
        bc[t] = s + bc2[t] + c1b[t];
    }
}

// ---------------- CSR build (by dst) ----------------
__global__ void csr_hist(const int* __restrict__ dst, int* cnt) {
    int e = blockIdx.x * 256 + threadIdx.x;
    if (e < EG) atomicAdd(&cnt[dst[e]], 1);
}
__global__ __launch_bounds__(1024) void csr_scan(const int* __restrict__ cnt,
                                                 int* __restrict__ rowp,
                                                 int* __restrict__ cur) {
    __shared__ int tmp[1024];
    const int t = threadIdx.x;
    const int base = t * 32;
    int local[32];
    int s = 0;
#pragma unroll
    for (int i = 0; i < 32; ++i) { local[i] = s; s += cnt[base + i]; }
    tmp[t] = s;
    __syncthreads();
    for (int o = 1; o < 1024; o <<= 1) {
        int v = (t >= o) ? tmp[t - o] : 0;
        __syncthreads();
        tmp[t] += v;
        __syncthreads();
    }
    int off = tmp[t] - s;  // exclusive prefix
#pragma unroll
    for (int i = 0; i < 32; ++i) {
        int p = off + local[i];
        rowp[base + i] = p;
        cur[base + i] = p;
    }
    if (t == 1023) rowp[NN] = off + s;
}
__global__ void csr_scatter(const int* __restrict__ src, const int* __restrict__ dst,
                            int* cur, int* __restrict__ esrc) {
    int e = blockIdx.x * 256 + threadIdx.x;
    if (e < EG) {
        int p = atomicAdd(&cur[dst[e]], 1);
        esrc[p] = src[e];
    }
}

// ---------------- fused GAT edge stage: softmax + aggregate + ELU ----------
__global__ __launch_bounds__(256) void gat_edge(const float* __restrict__ z,
                                                const int* __restrict__ rowp,
                                                const int* __restrict__ esrc,
                                                const float* __restrict__ es,
                                                const float* __restrict__ ed,
                                                const float* __restrict__ bias,
                                                float* __restrict__ out,
                                                unsigned short* __restrict__ outh,
                                                unsigned short* __restrict__ outl,
                                                const float* __restrict__ sw1,
                                                const float* __restrict__ sb1,
                                                const float* __restrict__ w12,
                                                const float* __restrict__ b12,
                                                float* __restrict__ sc1,
                                                float* __restrict__ sc2) {
    const int w = threadIdx.x >> 6;
    const int l = threadIdx.x & 63;
    const int b    = blockIdx.x;              // 0..8191
    const int xcd  = b & 7;
    const int slot = b >> 3;                  // 0..1023
    const int gph  = xcd + ((slot >> 7) << 3);
    const int d    = gph * NPG + ((slot & 127) << 2) + w;

    const int h  = l & 3;
    const int ei = l >> 2;
    const int h2 = l >> 4;
    const int beg = rowp[d];
    const int deg = rowp[d + 1] - beg;

    const float4 zv = *(const float4*)(z + (size_t)d * CC + 4 * l);
    float4 acc;

    if (deg <= 16 * NS) {
        const float edh = ed[d * HH + h];
        int   sidx[NS];
        float v[NS];
#pragma unroll
        for (int j = 0; j < NS; ++j) { sidx[j] = d; v[j] = 0.0f; }
        float vmax = -INFINITY, eself = 0.0f;
        float vself = 0.0f;
        if (ei == 0) {
            vself = leaky02(es[d * HH + h] + edh);
            vmax = vself;
        }
#pragma unroll
        for (int j = 0; j < NS; ++j) {
            int i = ei + 16 * j;
            if (i < deg) {
                sidx[j] = esrc[beg + i];
                v[j] = leaky02(es[sidx[j] * HH + h] + edh);
                vmax = fmaxf(vmax, v[j]);
            }
        }
#pragma unroll
        for (int o = 4; o <= 32; o <<= 1) vmax = fmaxf(vmax, __shfl_xor(vmax, o));
        float dsum = 0.0f;
#pragma unroll
        for (int j = 0; j < NS; ++j) {
            int i = ei + 16 * j;
            if (i < deg) { v[j] = __expf(v[j] - vmax); dsum += v[j]; }
        }
        if (ei == 0) { eself = __expf(vself - vmax); dsum += eself; }
#pragma unroll
        for (int o = 4; o <= 32; o <<= 1) dsum += __shfl_xor(dsum, o);
        const float inv = 1.0f / (dsum + 1e-16f);
#pragma unroll
        for (int j = 0; j < NS; ++j) v[j] *= inv;   // normalized alpha (0 = pad)
        eself *= inv;

        float aself = __shfl(eself, h2);
        acc = make_float4(aself * zv.x, aself * zv.y, aself * zv.z, aself * zv.w);
#pragma unroll
        for (int jj = 0; jj < 2 * NS; ++jj) {
            if (8 * jj < deg) {
                const int j = jj >> 1;
                const int lb = 32 * (jj & 1);
#pragma unroll
                for (int s = 0; s < 8; ++s) {
                    int   srcn = __builtin_amdgcn_readlane(sidx[j], lb + 4 * s);
                    float a    = __shfl(v[j], lb + 4 * s + h2);
                    const float4 zs = *(const float4*)(z + (size_t)srcn * CC + 4 * l);
                    acc.x = fmaf(a, zs.x, acc.x);
                    acc.y = fmaf(a, zs.y, acc.y);
                    acc.z = fmaf(a, zs.z, acc.z);
                    acc.w = fmaf(a, zs.w, acc.w);
                }
            }
        }
    } else {
        const float edh = ed[d * HH + h];
        float vmax = (ei == 0) ? leaky02(es[d * HH + h] + edh) : -INFINITY;
        for (int i = ei; i < deg; i += 16)
            vmax = fmaxf(vmax, leaky02(es[esrc[beg + i] * HH + h] + edh));
#pragma unroll
        for (int o = 4; o <= 32; o <<= 1) vmax = fmaxf(vmax, __shfl_xor(vmax, o));
        float dsum = (ei == 0) ? __expf(leaky02(es[d * HH + h] + edh) - vmax) : 0.0f;
        for (int i = ei; i < deg; i += 16)
            dsum += __expf(leaky02(es[esrc[beg + i] * HH + h] + edh) - vmax);
#pragma unroll
        for (int o = 4; o <= 32; o <<= 1) dsum += __shfl_xor(dsum, o);
        const float inv = 1.0f / (dsum + 1e-16f);

        const float vmaxc = __shfl(vmax, h2);
        const float invc  = __shfl(inv,  h2);
        const float edh4  = ed[d * HH + h2];
        float a0 = __expf(leaky02(es[d * HH + h2] + edh4) - vmaxc) * invc;
        acc = make_float4(a0 * zv.x, a0 * zv.y, a0 * zv.z, a0 * zv.w);
        for (int i = 0; i < deg; ++i) {
            int srcn = esrc[beg + i];
            float a = __expf(leaky02(es[srcn * HH + h2] + edh4) - vmaxc) * invc;
            float4 zs = *(const float4*)(z + (size_t)srcn * CC + 4 * l);
            acc.x = fmaf(a, zs.x, acc.x);
            acc.y = fmaf(a, zs.y, acc.y);
            acc.z = fmaf(a, zs.z, acc.z);
            acc.w = fmaf(a, zs.w, acc.w);
        }
    }

    const float4 bv = *(const float4*)(bias + 4 * l);
    float4 o;
    o.x = acc.x + bv.x; o.x = o.x > 0.0f ? o.x : expm1f(o.x);
    o.y = acc.y + bv.y; o.y = o.y > 0.0f ? o.y : expm1f(o.y);
    o.z = acc.z + bv.z; o.z = o.z > 0.0f ? o.z : expm1f(o.z);
    o.w = acc.w + bv.w; o.w = o.w > 0.0f ? o.w : expm1f(o.w);

    if (out) *(float4*)(out + (size_t)d * CC + 4 * l) = o;
    if (outh) {
        ushort4 uh, ul;
        split2(o.x, uh.x, ul.x);
        split2(o.y, uh.y, ul.y);
        split2(o.z, uh.z, ul.z);
        split2(o.w, uh.w, ul.w);
        ((ushort4*)outh)[(size_t)d * 64 + l] = uh;
        ((ushort4*)outl)[(size_t)d * 64 + l] = ul;
    }

    if (sc1) {
        const float4 s1 = *(const float4*)(sw1 + 4 * l);
        const float4 s2 = *(const float4*)(w12 + 4 * l);
        float r1 = o.x * s1.x + o.y * s1.y + o.z * s1.z + o.w * s1.w;
        float r2 = o.x * s2.x + o.y * s2.y + o.z * s2.z + o.w * s2.w;
#pragma unroll
        for (int off = 32; off >= 1; off >>= 1) {
            r1 += __shfl_xor(r1, off);
            r2 += __shfl_xor(r2, off);
        }
        if (l == 0) {
            sc1[d] = r1 + sb1[0];
            sc2[d] = r2 + b12[0];
        }
    }
}

// ---------------- top-k rank counting, 4 blocks/graph ---------------------
// Block b: graph b>>2, node strip (b&3)*128. Scores staged in LDS; each
// thread does 512 compares as 128 unrolled float4 broadcast reads.
// Matches lax.top_k sets (lower index wins ties); mask -> -inf + forced 0.
__global__ __launch_bounds__(128) void topk_ranks(const float* __restrict__ sc,
                                                  const int* __restrict__ mask,
                                                  int* __restrict__ sel, int k) {
    __shared__ float s4[NPG];
    const int b = blockIdx.x;
    const int g = b >> 2;
    const int p = b & 3;
    const int t = threadIdx.x;   // 0..127
    float4 v = *(const float4*)(sc + (size_t)g * NPG + t * 4);
    int4 mk = make_int4(1, 1, 1, 1);
    if (mask) {
        mk = *(const int4*)(mask + (size_t)g * NPG + t * 4);
        v.x = mk.x ? v.x : -INFINITY;
        v.y = mk.y ? v.y : -INFINITY;
        v.z = mk.z ? v.z : -INFINITY;
        v.w = mk.w ? v.w : -INFINITY;
    }
    *(float4*)(s4 + t * 4) = v;
    __syncthreads();
    const int n = p * 128 + t;      // graph-local node index
    const float my = s4[n];
    int rank = 0;
#pragma unroll 16
    for (int j4 = 0; j4 < NPG / 4; ++j4) {
        const float4 sv = *(const float4*)(s4 + j4 * 4);
        const int jb = j4 * 4;
        rank += (sv.x > my) || (sv.x == my && (jb + 0) < n);
        rank += (sv.y > my) || (sv.y == my && (jb + 1) < n);
        rank += (sv.z > my) || (sv.z == my && (jb + 2) < n);
        rank += (sv.w > my) || (sv.w == my && (jb + 3) < n);
    }
    int ok = rank < k;
    if (mask && !mask[(size_t)g * NPG + n]) ok = 0;
    sel[(size_t)g * NPG + n] = ok;
}

// ---------------- masked partial mean, 4 blocks/graph ---------------------
__global__ __launch_bounds__(256) void pool_mean(const float* __restrict__ feat,
                                                 const int* __restrict__ sel2,
                                                 float* __restrict__ partial) {
    __shared__ float vbuf[4][CC];
    __shared__ int keep[128];
    const int b = blockIdx.x;    // 0..255
    const int g = b >> 2, p = b & 3;
    const int i = threadIdx.x;
    const int r = i >> 6, c4 = i & 63;
    if (i < 128) keep[i] = sel2[(size_t)g * NPG + p * 128 + i];
    __syncthreads();
    float4 acc = make_float4(0.f, 0.f, 0.f, 0.f);
    const float4* f4 = (const float4*)(feat + ((size_t)g * NPG + p * 128) * CC);
    for (int j = r; j < 128; j += 4) {
        if (keep[j]) {
            float4 v = f4[j * 64 + c4];
            acc.x += v.x; acc.y += v.y; acc.z += v.z; acc.w += v.w;
        }
    }
    vbuf[r][c4 * 4 + 0] = acc.x;
    vbuf[r][c4 * 4 + 1] = acc.y;
    vbuf[r][c4 * 4 + 2] = acc.z;
    vbuf[r][c4 * 4 + 3] = acc.w;
    __syncthreads();
    partial[(size_t)(g * 4 + p) * CC + i] =
        vbuf[0][i] + vbuf[1][i] + vbuf[2][i] + vbuf[3][i];
}

// ---------------- folded head: relu(mean@Wc+bc)@c2w+c2b -> log_softmax ----
__global__ __launch_bounds__(256) void head_k(const float* __restrict__ partial,
                                              const float* __restrict__ Wc,
                                              const float* __restrict__ bc,
                                              const float* __restrict__ c2w,
                                              const float* __restrict__ c2b,
                                              float* __restrict__ out) {
    __shared__ float v0[CC];
    __shared__ float part[4][64];
    __shared__ float v2[64];
    const int g = blockIdx.x;
    const int i = threadIdx.x;
    float tsum = partial[(size_t)(g * 4 + 0) * CC + i] +
                 partial[(size_t)(g * 4 + 1) * CC + i] +
                 partial[(size_t)(g * 4 + 2) * CC + i] +
                 partial[(size_t)(g * 4 + 3) * CC + i];
    v0[i] = tsum * (1.0f / KP2);
    __syncthreads();
    {
        const int q = i >> 6, cth = i & 63;
        float p = 0.0f;
        for (int j = q * 64; j < q * 64 + 64; ++j)
            p = fmaf(v0[j], Wc[j * 64 + cth], p);
        part[q][cth] = p;
    }
    __syncthreads();
    if (i < 64) {
        float u = bc[i];
#pragma unroll
        for (int q = 0; q < 4; ++q) u += part[q][i];
        v2[i] = fmaxf(u, 0.0f);
    }
    __syncthreads();
    if (i < 2) {
        float o = c2b[i];
        for (int j = 0; j < 64; ++j) o = fmaf(v2[j], c2w[j * 2 + i], o);
        part[0][i] = o;
    }
    __syncthreads();
    if (i == 0) {
        float a = part[0][0], bq = part[0][1];
        float mx = fmaxf(a, bq);
        float lse = mx + logf(expf(a - mx) + expf(bq - mx));
        out[g * 2 + 0] = a - lse;
        out[g * 2 + 1] = bq - lse;
    }
}

// ---------------- launcher ----------------
extern "C" void kernel_launch(void* const* d_in, const int* in_sizes, int n_in,
                              void* d_out, int out_size, void* d_ws, size_t ws_size,
                              hipStream_t stream) {
    const float* x      = (const float*)d_in[0];
    const int*   ei     = (const int*)d_in[1];
    const int*   src    = ei;
    const int*   dst    = ei + EG;
    const float* W1     = (const float*)d_in[3];
    const float* a_src1 = (const float*)d_in[4];
    const float* a_dst1 = (const float*)d_in[5];
    const float* b1     = (const float*)d_in[6];
    const float* W2     = (const float*)d_in[7];
    const float* a_src2 = (const float*)d_in[8];
    const float* a_dst2 = (const float*)d_in[9];
    const float* b2     = (const float*)d_in[10];
    const float* p1_sw  = (const float*)d_in[11];
    const float* p1_sb  = (const float*)d_in[12];
    const float* p1_tw  = (const float*)d_in[13];
    const float* p1_tb  = (const float*)d_in[14];
    const float* p2_sw  = (const float*)d_in[15];
    const float* p2_sb  = (const float*)d_in[16];
    const float* p2_tw  = (const float*)d_in[17];
    const float* p2_tb  = (const float*)d_in[18];
    const float* c1w    = (const float*)d_in[19];
    const float* c1b    = (const float*)d_in[20];
    const float* c2w    = (const float*)d_in[21];
    const float* c2b    = (const float*)d_in[22];
    float* out = (float*)d_out;

    // workspace layout
    float* ws = (float*)d_ws;
    unsigned short* xhi = (unsigned short*)ws;          // NN*FIN ushorts
    unsigned short* xlo = xhi + (size_t)NN * FIN;       // NN*FIN
    float* z = ws + (size_t)NN * FIN;                   // NN*CC floats
    float* fregion = z + (size_t)NN * CC;               // NN*CC floats (32 MB)
    unsigned short* fhi = (unsigned short*)fregion;     //   phase 1: fhi/flo bf16
    unsigned short* flo = fhi + (size_t)NN * CC;
    float* featF = fregion;                             //   phase 2: fp32 feat (alias)
    float* wsp = fregion + (size_t)NN * CC;
    unsigned short* w1ph = (unsigned short*)wsp;        // 256*128 packed
    unsigned short* w1pl = w1ph + 256 * FIN;
    unsigned short* w2ph = w1pl + 256 * FIN;            // 256*256 packed
    unsigned short* w2pl = w2ph + 256 * CC;
    float* es  = (float*)(w2pl + 256 * CC);             // N*H
    float* ed  = es + NN * HH;
    int* cnt   = (int*)(ed + NN * HH);                  // N
    int* rowp  = cnt + NN;                              // N+1
    int* cur   = rowp + NN + 1;                         // N
    int* esrc  = cur + NN;                              // E
    float* sc1 = (float*)(esrc + EG);                   // N
    float* sc2 = sc1 + NN;                              // N
    int* sel1  = (int*)(sc2 + NN);                      // N
    int* sel2  = sel1 + NN;                             // N
    float* w12 = (float*)(sel2 + NN);                   // C
    float* b12 = w12 + CC;                              // 1 (padded 64)
    float* T   = b12 + 64;                              // 256*64
    float* Wc  = T + CC * 64;                           // 256*64
    float* bc2 = Wc + CC * 64;                          // 64
    float* bcv = bc2 + 64;                              // 64
    float* partial = bcv + 64;                          // BG*4*CC

    // ---- prep + conversions + CSR build ----
    prep<<<194, 256, 0, stream>>>(cnt, p1_tw, p2_sw, p1_tb, p2_sb, w12, b12,
                                  p2_tw, c1w, p2_tb, T, bc2);
    conv_split<<<(NN * FIN / 4 + 255) / 256, 256, 0, stream>>>(x, xhi, xlo, NN * FIN / 4);
    conv_wpack<<<48, 256, 0, stream>>>(W1, W2, w1ph, w1pl, w2ph, w2pl);
    csr_hist<<<(EG + 255) / 256, 256, 0, stream>>>(dst, cnt);
    csr_scan<<<1, 1024, 0, stream>>>(cnt, rowp, cur);
    csr_scatter<<<(EG + 255) / 256, 256, 0, stream>>>(src, dst, cur, esrc);
    fold_W<<<65, 256, 0, stream>>>(p1_tw, T, p1_tb, bc2, c1b, Wc, bcv);

    // ---- GAT layer 1 ----
    gemm_mfma_attn<<<NN / 32, 256, 0, stream>>>(xhi, xlo, w1ph, w1pl, z, FIN,
                                                a_src1, a_dst1, es, ed);
    gat_edge<<<NN / 4, 256, 0, stream>>>(z, rowp, esrc, es, ed, b1,
                                         nullptr, fhi, flo,
                                         nullptr, nullptr, nullptr, nullptr,
                                         nullptr, nullptr);

    // ---- GAT layer 2 ----
    gemm_mfma_attn<<<NN / 32, 256, 0, stream>>>(fhi, flo, w2ph, w2pl, z, CC,
                                                a_src2, a_dst2, es, ed);
    gat_edge<<<NN / 4, 256, 0, stream>>>(z, rowp, esrc, es, ed, b2,
                                         featF, nullptr, nullptr,
                                         p1_sw, p1_sb, w12, b12, sc1, sc2);

    // ---- parallel pooling + folded head ----
    topk_ranks<<<BG * 4, 128, 0, stream>>>(sc1, nullptr, sel1, KP1);
    topk_ranks<<<BG * 4, 128, 0, stream>>>(sc2, sel1, sel2, KP2);
    pool_mean<<<BG * 4, 256, 0, stream>>>(featF, sel2, partial);
    head_k<<<BG, 256, 0, stream>>>(partial, Wc, bcv, c2w, c2b, out);
}

// Round 13
// 299.850 us; speedup vs baseline: 1.3889x; 1.1349x over previous
//
#include <hip/hip_runtime.h>
#include <hip/hip_bf16.h>
#include <math.h>

// ---------------- problem constants ----------------
constexpr int NN  = 32768;   // nodes
constexpr int BG  = 64;      // graphs
constexpr int NPG = 512;     // nodes per graph
constexpr int EG  = 524288;  // edges
constexpr int EPG = EG / BG; // 8192 edges per graph
constexpr int HH  = 4;       // heads
constexpr int FH  = 64;      // per-head dim
constexpr int CC  = 256;     // H*Fh
constexpr int FIN = 128;
constexpr int KP1 = 256;     // pool1 k
constexpr int KP2 = 128;     // pool2 k
constexpr int NS  = 4;       // register edge slots: fast path deg <= 64

typedef __attribute__((ext_vector_type(8))) short short8;  // 8 bf16 = 4 VGPRs
typedef __attribute__((ext_vector_type(4))) float f32x4;

__device__ inline float leaky02(float v) { return v > 0.0f ? v : 0.2f * v; }

__device__ inline unsigned short f2bf(float v) {
    __hip_bfloat16 h = __float2bfloat16(v);
    return *(unsigned short*)&h;
}
__device__ inline float bf2f(unsigned short u) {
    __hip_bfloat16 h;
    *(unsigned short*)&h = u;
    return __bfloat162float(h);
}
__device__ inline void split2(float v, unsigned short& hi, unsigned short& lo) {
    hi = f2bf(v);
    lo = f2bf(v - bf2f(hi));
}
// split 8 consecutive floats into hi/lo bf16 fragments (A-operand order)
__device__ inline void split8(const float* p, short8& hi, short8& lo) {
    const float4 f0 = *(const float4*)p;
    const float4 f1 = *(const float4*)(p + 4);
    unsigned short h, l;
    split2(f0.x, h, l); hi[0] = (short)h; lo[0] = (short)l;
    split2(f0.y, h, l); hi[1] = (short)h; lo[1] = (short)l;
    split2(f0.z, h, l); hi[2] = (short)h; lo[2] = (short)l;
    split2(f0.w, h, l); hi[3] = (short)h; lo[3] = (short)l;
    split2(f1.x, h, l); hi[4] = (short)h; lo[4] = (short)l;
    split2(f1.y, h, l); hi[5] = (short)h; lo[5] = (short)l;
    split2(f1.z, h, l); hi[6] = (short)h; lo[6] = (short)l;
    split2(f1.w, h, l); hi[7] = (short)h; lo[7] = (short)l;
}

// ---------------- W pack: fp32 -> FRAGMENT-PACKED split bf16 --------------
// Packed layout: [nt (16 cols)][kg (32 k)][lane l][j]:
//   n = nt*16 + (l&15), k = kg*32 + (l>>4)*8 + j
__global__ __launch_bounds__(256) void conv_wpack(const float* __restrict__ W1,
                                                  const float* __restrict__ W2,
                                                  unsigned short* __restrict__ w1ph,
                                                  unsigned short* __restrict__ w1pl,
                                                  unsigned short* __restrict__ w2ph,
                                                  unsigned short* __restrict__ w2pl) {
    int idx = blockIdx.x * 256 + threadIdx.x;      // 0 .. 12287
    if (idx < 4096) {                              // W1: 16 nt x 4 kg x 64 l
        const int nt = idx >> 8, rem = idx & 255;
        const int kg = rem >> 6, l = rem & 63;
        const int n = nt * 16 + (l & 15);
        const int kb = kg * 32 + (l >> 4) * 8;
        unsigned short h[8], lo[8];
#pragma unroll
        for (int j = 0; j < 8; ++j) split2(W1[(kb + j) * CC + n], h[j], lo[j]);
#pragma unroll
        for (int j = 0; j < 8; ++j) {
            w1ph[(size_t)idx * 8 + j] = h[j];
            w1pl[(size_t)idx * 8 + j] = lo[j];
        }
    } else if (idx < 12288) {                      // W2: 16 nt x 8 kg x 64 l
        const int i2 = idx - 4096;
        const int nt = i2 >> 9, rem = i2 & 511;
        const int kg = rem >> 6, l = rem & 63;
        const int n = nt * 16 + (l & 15);
        const int kb = kg * 32 + (l >> 4) * 8;
        unsigned short h[8], lo[8];
#pragma unroll
        for (int j = 0; j < 8; ++j) split2(W2[(kb + j) * CC + n], h[j], lo[j]);
#pragma unroll
        for (int j = 0; j < 8; ++j) {
            w2ph[(size_t)i2 * 8 + j] = h[j];
            w2pl[(size_t)i2 * 8 + j] = lo[j];
        }
    }
}

// ---------------- MFMA GEMM (layer 2): A = split-bf16 pair ----------------
__global__ __launch_bounds__(256, 4) void gemm_mfma_attn(
        const unsigned short* __restrict__ Ahi, const unsigned short* __restrict__ Alo,
        const unsigned short* __restrict__ Bph, const unsigned short* __restrict__ Bpl,
        float* __restrict__ Cm, int K,
        const float* __restrict__ a_src, const float* __restrict__ a_dst,
        float* __restrict__ es, float* __restrict__ ed) {
    const int t = threadIdx.x;
    const int w = t >> 6;          // wave = col strip = head
    const int l = t & 63;
    const int bx   = blockIdx.x;               // 0..1023
    const int xcd  = bx & 7;
    const int slot = bx >> 3;                  // 0..127
    const int gph  = xcd + ((slot >> 4) << 3); // graph
    const int row0 = gph * NPG + ((slot & 15) << 5);
    const int m = l & 15;
    const int q = l >> 4;
    const int ncol0 = w * 64;
    const int KG = K >> 5;

    const unsigned short* aH0 = Ahi + (size_t)(row0 + m) * K + q * 8;
    const unsigned short* aL0 = Alo + (size_t)(row0 + m) * K + q * 8;
    const unsigned short* aH1 = aH0 + (size_t)16 * K;
    const unsigned short* aL1 = aL0 + (size_t)16 * K;

    f32x4 acc0[4], acc1[4];
#pragma unroll
    for (int c = 0; c < 4; ++c) {
        acc0[c] = (f32x4){0.f, 0.f, 0.f, 0.f};
        acc1[c] = (f32x4){0.f, 0.f, 0.f, 0.f};
    }

    for (int kg = 0; kg < KG; ++kg) {
        const int ko = kg * 32;
        short8 ah0 = *(const short8*)(aH0 + ko);
        short8 al0 = *(const short8*)(aL0 + ko);
        short8 ah1 = *(const short8*)(aH1 + ko);
        short8 al1 = *(const short8*)(aL1 + ko);
#pragma unroll
        for (int c = 0; c < 4; ++c) {
            const int nt = (w << 2) + c;
            const size_t boff = ((size_t)(nt * KG + kg) * 64 + l) * 8;
            short8 bh = *(const short8*)(Bph + boff);
            short8 bl = *(const short8*)(Bpl + boff);
            acc0[c] = __builtin_amdgcn_mfma_f32_16x16x32_bf16(ah0, bh, acc0[c], 0, 0, 0);
            acc0[c] = __builtin_amdgcn_mfma_f32_16x16x32_bf16(ah0, bl, acc0[c], 0, 0, 0);
            acc0[c] = __builtin_amdgcn_mfma_f32_16x16x32_bf16(al0, bh, acc0[c], 0, 0, 0);
            acc1[c] = __builtin_amdgcn_mfma_f32_16x16x32_bf16(ah1, bh, acc1[c], 0, 0, 0);
            acc1[c] = __builtin_amdgcn_mfma_f32_16x16x32_bf16(ah1, bl, acc1[c], 0, 0, 0);
            acc1[c] = __builtin_amdgcn_mfma_f32_16x16x32_bf16(al1, bh, acc1[c], 0, 0, 0);
        }
    }

#pragma unroll
    for (int c = 0; c < 4; ++c)
#pragma unroll
        for (int r = 0; r < 4; ++r) {
            Cm[(size_t)(row0 + q * 4 + r) * CC + ncol0 + c * 16 + m] = acc0[c][r];
            Cm[(size_t)(row0 + 16 + q * 4 + r) * CC + ncol0 + c * 16 + m] = acc1[c][r];
        }

    float asv[4], adv[4];
#pragma unroll
    for (int c = 0; c < 4; ++c) {
        asv[c] = a_src[ncol0 + c * 16 + m];
        adv[c] = a_dst[ncol0 + c * 16 + m];
    }
#pragma unroll
    for (int r = 0; r < 4; ++r) {
        float ps0 = 0.f, pd0 = 0.f, ps1 = 0.f, pd1 = 0.f;
#pragma unroll
        for (int c = 0; c < 4; ++c) {
            ps0 = fmaf(acc0[c][r], asv[c], ps0);
            pd0 = fmaf(acc0[c][r], adv[c], pd0);
            ps1 = fmaf(acc1[c][r], asv[c], ps1);
            pd1 = fmaf(acc1[c][r], adv[c], pd1);
        }
#pragma unroll
        for (int o = 8; o >= 1; o >>= 1) {
            ps0 += __shfl_down(ps0, o, 16);
            pd0 += __shfl_down(pd0, o, 16);
            ps1 += __shfl_down(ps1, o, 16);
            pd1 += __shfl_down(pd1, o, 16);
        }
        if (m == 0) {
            es[(row0 + q * 4 + r) * HH + w] = ps0;
            ed[(row0 + q * 4 + r) * HH + w] = pd0;
            es[(row0 + 16 + q * 4 + r) * HH + w] = ps1;
            ed[(row0 + 16 + q * 4 + r) * HH + w] = pd1;
        }
    }
}

// ---------------- MFMA GEMM (layer 1): A = fp32, split in-register --------
__global__ __launch_bounds__(256, 4) void gemm_mfma_attn_f32(
        const float* __restrict__ Af,
        const unsigned short* __restrict__ Bph, const unsigned short* __restrict__ Bpl,
        float* __restrict__ Cm, int K,
        const float* __restrict__ a_src, const float* __restrict__ a_dst,
        float* __restrict__ es, float* __restrict__ ed) {
    const int t = threadIdx.x;
    const int w = t >> 6;
    const int l = t & 63;
    const int bx   = blockIdx.x;
    const int xcd  = bx & 7;
    const int slot = bx >> 3;
    const int gph  = xcd + ((slot >> 4) << 3);
    const int row0 = gph * NPG + ((slot & 15) << 5);
    const int m = l & 15;
    const int q = l >> 4;
    const int ncol0 = w * 64;
    const int KG = K >> 5;

    const float* aF0 = Af + (size_t)(row0 + m) * K + q * 8;
    const float* aF1 = aF0 + (size_t)16 * K;

    f32x4 acc0[4], acc1[4];
#pragma unroll
    for (int c = 0; c < 4; ++c) {
        acc0[c] = (f32x4){0.f, 0.f, 0.f, 0.f};
        acc1[c] = (f32x4){0.f, 0.f, 0.f, 0.f};
    }

    for (int kg = 0; kg < KG; ++kg) {
        const int ko = kg * 32;
        short8 ah0, al0, ah1, al1;
        split8(aF0 + ko, ah0, al0);
        split8(aF1 + ko, ah1, al1);
#pragma unroll
        for (int c = 0; c < 4; ++c) {
            const int nt = (w << 2) + c;
            const size_t boff = ((size_t)(nt * KG + kg) * 64 + l) * 8;
            short8 bh = *(const short8*)(Bph + boff);
            short8 bl = *(const short8*)(Bpl + boff);
            acc0[c] = __builtin_amdgcn_mfma_f32_16x16x32_bf16(ah0, bh, acc0[c], 0, 0, 0);
            acc0[c] = __builtin_amdgcn_mfma_f32_16x16x32_bf16(ah0, bl, acc0[c], 0, 0, 0);
            acc0[c] = __builtin_amdgcn_mfma_f32_16x16x32_bf16(al0, bh, acc0[c], 0, 0, 0);
            acc1[c] = __builtin_amdgcn_mfma_f32_16x16x32_bf16(ah1, bh, acc1[c], 0, 0, 0);
            acc1[c] = __builtin_amdgcn_mfma_f32_16x16x32_bf16(ah1, bl, acc1[c], 0, 0, 0);
            acc1[c] = __builtin_amdgcn_mfma_f32_16x16x32_bf16(al1, bh, acc1[c], 0, 0, 0);
        }
    }

#pragma unroll
    for (int c = 0; c < 4; ++c)
#pragma unroll
        for (int r = 0; r < 4; ++r) {
            Cm[(size_t)(row0 + q * 4 + r) * CC + ncol0 + c * 16 + m] = acc0[c][r];
            Cm[(size_t)(row0 + 16 + q * 4 + r) * CC + ncol0 + c * 16 + m] = acc1[c][r];
        }

    float asv[4], adv[4];
#pragma unroll
    for (int c = 0; c < 4; ++c) {
        asv[c] = a_src[ncol0 + c * 16 + m];
        adv[c] = a_dst[ncol0 + c * 16 + m];
    }
#pragma unroll
    for (int r = 0; r < 4; ++r) {
        float ps0 = 0.f, pd0 = 0.f, ps1 = 0.f, pd1 = 0.f;
#pragma unroll
        for (int c = 0; c < 4; ++c) {
            ps0 = fmaf(acc0[c][r], asv[c], ps0);
            pd0 = fmaf(acc0[c][r], adv[c], pd0);
            ps1 = fmaf(acc1[c][r], asv[c], ps1);
            pd1 = fmaf(acc1[c][r], adv[c], pd1);
        }
#pragma unroll
        for (int o = 8; o >= 1; o >>= 1) {
            ps0 += __shfl_down(ps0, o, 16);
            pd0 += __shfl_down(pd0, o, 16);
            ps1 += __shfl_down(ps1, o, 16);
            pd1 += __shfl_down(pd1, o, 16);
        }
        if (m == 0) {
            es[(row0 + q * 4 + r) * HH + w] = ps0;
            ed[(row0 + q * 4 + r) * HH + w] = pd0;
            es[(row0 + 16 + q * 4 + r) * HH + w] = ps1;
            ed[(row0 + 16 + q * 4 + r) * HH + w] = pd1;
        }
    }
}

// ---------------- prep: w12 + T = tw2@c1w + bc2 = tb2@c1w ------------------
// block 0: w12/b12. blocks 1..64: T rows (4/block). block 65: bc2.
__global__ __launch_bounds__(256) void prep(const float* __restrict__ tw1,
                                            const float* __restrict__ sw2,
                                            const float* __restrict__ tb1,
                                            const float* __restrict__ sb2,
                                            float* __restrict__ w12,
                                            float* __restrict__ b12,
                                            const float* __restrict__ tw2,
                                            const float* __restrict__ c1w,
                                            const float* __restrict__ tb2,
                                            float* __restrict__ T,
                                            float* __restrict__ bc2) {
    const int b = blockIdx.x;
    const int t = threadIdx.x;
    if (b == 0) {
        float s = 0.0f;
        for (int o = 0; o < CC; ++o) s += tw1[t * CC + o] * sw2[o];
        w12[t] = s;
        if (t == 0) {
            float bb = 0.0f;
            for (int o = 0; o < CC; ++o) bb += tb1[o] * sw2[o];
            *b12 = bb + sb2[0];
        }
    } else if (b < 65) {
        const int r = (b - 1) * 4 + (t >> 6);
        const int cth = t & 63;
        float s = 0.0f;
        for (int j = 0; j < CC; ++j) s = fmaf(tw2[r * CC + j], c1w[j * 64 + cth], s);
        T[r * 64 + cth] = s;
    } else if (t < 64) {
        float s = 0.0f;
        for (int j = 0; j < CC; ++j) s = fmaf(tb2[j], c1w[j * 64 + t], s);
        bc2[t] = s;
    }
}

// ---------------- fold_W: Wc = tw1@T, bc = tb1@T + bc2 + c1b --------------
__global__ __launch_bounds__(256) void fold_W(const float* __restrict__ tw1,
                                              const float* __restrict__ T,
                                              const float* __restrict__ tb1,
                                              const float* __restrict__ bc2,
                                              const float* __restrict__ c1b,
                                              float* __restrict__ Wc,
                                              float* __restrict__ bc) {
    const int b = blockIdx.x;
    const int t = threadIdx.x;
    if (b < 64) {
        const int r = b * 4 + (t >> 6);
        const int cth = t & 63;
        float s = 0.0f;
        for (int j = 0; j < CC; ++j) s = fmaf(tw1[r * CC + j], T[j * 64 + cth], s);
        Wc[r * 64 + cth] = s;
    } else if (t < 64) {
        float s = 0.0f;
        for (int j = 0; j < CC; ++j) s = fmaf(tb1[j], T[j * 64 + t], s);
        bc[t] = s + bc2[t] + c1b[t];
    }
}

// ---------------- single-kernel CSR build: one block per graph ------------
// Edges are graph-contiguous (EPG per graph, dst within graph). LDS
// histogram -> LDS Hillis-Steele scan -> LDS-cursor scatter. No global
// atomics, no separate zero/scan kernels.
__global__ __launch_bounds__(1024) void csr_build(const int* __restrict__ src,
                                                  const int* __restrict__ dst,
                                                  int* __restrict__ rowp,
                                                  int* __restrict__ esrc) {
    __shared__ int lcnt[NPG];
    __shared__ int lofs[NPG];
    const int g = blockIdx.x;
    const int t = threadIdx.x;
    const int ebase = g * EPG;
    const int nbase = g * NPG;
    if (t < NPG) lcnt[t] = 0;
    __syncthreads();
    int ds[EPG / 1024];
#pragma unroll
    for (int j = 0; j < EPG / 1024; ++j) {
        ds[j] = dst[ebase + t + 1024 * j] - nbase;
        atomicAdd(&lcnt[ds[j]], 1);
    }
    __syncthreads();
    if (t < NPG) lofs[t] = lcnt[t];
    __syncthreads();
    for (int o = 1; o < NPG; o <<= 1) {
        int v = 0;
        if (t < NPG && t >= o) v = lofs[t - o];
        __syncthreads();
        if (t < NPG) lofs[t] += v;
        __syncthreads();
    }
    if (t < NPG) {
        int ex = lofs[t] - lcnt[t];         // exclusive prefix
        rowp[nbase + t] = ebase + ex;
        lcnt[t] = ex;                        // reuse as cursor
    }
    if (g == BG - 1 && t == 0) rowp[NN] = EG;
    __syncthreads();
#pragma unroll
    for (int j = 0; j < EPG / 1024; ++j) {
        int p = atomicAdd(&lcnt[ds[j]], 1);
        esrc[ebase + p] = src[ebase + t + 1024 * j];
    }
}

// ---------------- fused GAT edge stage: softmax + aggregate + ELU ----------
__global__ __launch_bounds__(256) void gat_edge(const float* __restrict__ z,
                                                const int* __restrict__ rowp,
                                                const int* __restrict__ esrc,
                                                const float* __restrict__ es,
                                                const float* __restrict__ ed,
                                                const float* __restrict__ bias,
                                                float* __restrict__ out,
                                                unsigned short* __restrict__ outh,
                                                unsigned short* __restrict__ outl,
                                                const float* __restrict__ sw1,
                                                const float* __restrict__ sb1,
                                                const float* __restrict__ w12,
                                                const float* __restrict__ b12,
                                                float* __restrict__ sc1,
                                                float* __restrict__ sc2) {
    const int w = threadIdx.x >> 6;
    const int l = threadIdx.x & 63;
    const int b    = blockIdx.x;              // 0..8191
    const int xcd  = b & 7;
    const int slot = b >> 3;                  // 0..1023
    const int gph  = xcd + ((slot >> 7) << 3);
    const int d    = gph * NPG + ((slot & 127) << 2) + w;

    const int h  = l & 3;
    const int ei = l >> 2;
    const int h2 = l >> 4;
    const int beg = rowp[d];
    const int deg = rowp[d + 1] - beg;

    const float4 zv = *(const float4*)(z + (size_t)d * CC + 4 * l);
    float4 acc;

    if (deg <= 16 * NS) {
        const float edh = ed[d * HH + h];
        int   sidx[NS];
        float v[NS];
#pragma unroll
        for (int j = 0; j < NS; ++j) { sidx[j] = d; v[j] = 0.0f; }
        float vmax = -INFINITY, eself = 0.0f;
        float vself = 0.0f;
        if (ei == 0) {
            vself = leaky02(es[d * HH + h] + edh);
            vmax = vself;
        }
#pragma unroll
        for (int j = 0; j < NS; ++j) {
            int i = ei + 16 * j;
            if (i < deg) {
                sidx[j] = esrc[beg + i];
                v[j] = leaky02(es[sidx[j] * HH + h] + edh);
                vmax = fmaxf(vmax, v[j]);
            }
        }
#pragma unroll
        for (int o = 4; o <= 32; o <<= 1) vmax = fmaxf(vmax, __shfl_xor(vmax, o));
        float dsum = 0.0f;
#pragma unroll
        for (int j = 0; j < NS; ++j) {
            int i = ei + 16 * j;
            if (i < deg) { v[j] = __expf(v[j] - vmax); dsum += v[j]; }
        }
        if (ei == 0) { eself = __expf(vself - vmax); dsum += eself; }
#pragma unroll
        for (int o = 4; o <= 32; o <<= 1) dsum += __shfl_xor(dsum, o);
        const float inv = 1.0f / (dsum + 1e-16f);
#pragma unroll
        for (int j = 0; j < NS; ++j) v[j] *= inv;   // normalized alpha (0 = pad)
        eself *= inv;

        float aself = __shfl(eself, h2);
        acc = make_float4(aself * zv.x, aself * zv.y, aself * zv.z, aself * zv.w);
#pragma unroll
        for (int jj = 0; jj < 2 * NS; ++jj) {
            if (8 * jj < deg) {
                const int j = jj >> 1;
                const int lb = 32 * (jj & 1);
#pragma unroll
                for (int s = 0; s < 8; ++s) {
                    int   srcn = __builtin_amdgcn_readlane(sidx[j], lb + 4 * s);
                    float a    = __shfl(v[j], lb + 4 * s + h2);
                    const float4 zs = *(const float4*)(z + (size_t)srcn * CC + 4 * l);
                    acc.x = fmaf(a, zs.x, acc.x);
                    acc.y = fmaf(a, zs.y, acc.y);
                    acc.z = fmaf(a, zs.z, acc.z);
                    acc.w = fmaf(a, zs.w, acc.w);
                }
            }
        }
    } else {
        const float edh = ed[d * HH + h];
        float vmax = (ei == 0) ? leaky02(es[d * HH + h] + edh) : -INFINITY;
        for (int i = ei; i < deg; i += 16)
            vmax = fmaxf(vmax, leaky02(es[esrc[beg + i] * HH + h] + edh));
#pragma unroll
        for (int o = 4; o <= 32; o <<= 1) vmax = fmaxf(vmax, __shfl_xor(vmax, o));
        float dsum = (ei == 0) ? __expf(leaky02(es[d * HH + h] + edh) - vmax) : 0.0f;
        for (int i = ei; i < deg; i += 16)
            dsum += __expf(leaky02(es[esrc[beg + i] * HH + h] + edh) - vmax);
#pragma unroll
        for (int o = 4; o <= 32; o <<= 1) dsum += __shfl_xor(dsum, o);
        const float inv = 1.0f / (dsum + 1e-16f);

        const float vmaxc = __shfl(vmax, h2);
        const float invc  = __shfl(inv,  h2);
        const float edh4  = ed[d * HH + h2];
        float a0 = __expf(leaky02(es[d * HH + h2] + edh4) - vmaxc) * invc;
        acc = make_float4(a0 * zv.x, a0 * zv.y, a0 * zv.z, a0 * zv.w);
        for (int i = 0; i < deg; ++i) {
            int srcn = esrc[beg + i];
            float a = __expf(leaky02(es[srcn * HH + h2] + edh4) - vmaxc) * invc;
            float4 zs = *(const float4*)(z + (size_t)srcn * CC + 4 * l);
            acc.x = fmaf(a, zs.x, acc.x);
            acc.y = fmaf(a, zs.y, acc.y);
            acc.z = fmaf(a, zs.z, acc.z);
            acc.w = fmaf(a, zs.w, acc.w);
        }
    }

    const float4 bv = *(const float4*)(bias + 4 * l);
    float4 o;
    o.x = acc.x + bv.x; o.x = o.x > 0.0f ? o.x : expm1f(o.x);
    o.y = acc.y + bv.y; o.y = o.y > 0.0f ? o.y : expm1f(o.y);
    o.z = acc.z + bv.z; o.z = o.z > 0.0f ? o.z : expm1f(o.z);
    o.w = acc.w + bv.w; o.w = o.w > 0.0f ? o.w : expm1f(o.w);

    if (out) *(float4*)(out + (size_t)d * CC + 4 * l) = o;
    if (outh) {
        ushort4 uh, ul;
        split2(o.x, uh.x, ul.x);
        split2(o.y, uh.y, ul.y);
        split2(o.z, uh.z, ul.z);
        split2(o.w, uh.w, ul.w);
        ((ushort4*)outh)[(size_t)d * 64 + l] = uh;
        ((ushort4*)outl)[(size_t)d * 64 + l] = ul;
    }

    if (sc1) {
        const float4 s1 = *(const float4*)(sw1 + 4 * l);
        const float4 s2 = *(const float4*)(w12 + 4 * l);
        float r1 = o.x * s1.x + o.y * s1.y + o.z * s1.z + o.w * s1.w;
        float r2 = o.x * s2.x + o.y * s2.y + o.z * s2.z + o.w * s2.w;
#pragma unroll
        for (int off = 32; off >= 1; off >>= 1) {
            r1 += __shfl_xor(r1, off);
            r2 += __shfl_xor(r2, off);
        }
        if (l == 0) {
            sc1[d] = r1 + sb1[0];
            sc2[d] = r2 + b12[0];
        }
    }
}

// ---------------- top-k1 rank counting, 4 blocks/graph --------------------
__global__ __launch_bounds__(128) void topk_ranks(const float* __restrict__ sc,
                                                  int* __restrict__ sel, int k) {
    __shared__ float s4[NPG];
    const int b = blockIdx.x;
    const int g = b >> 2;
    const int p = b & 3;
    const int t = threadIdx.x;   // 0..127
    float4 v = *(const float4*)(sc + (size_t)g * NPG + t * 4);
    *(float4*)(s4 + t * 4) = v;
    __syncthreads();
    const int n = p * 128 + t;
    const float my = s4[n];
    int rank = 0;
#pragma unroll 16
    for (int j4 = 0; j4 < NPG / 4; ++j4) {
        const float4 sv = *(const float4*)(s4 + j4 * 4);
        const int jb = j4 * 4;
        rank += (sv.x > my) || (sv.x == my && (jb + 0) < n);
        rank += (sv.y > my) || (sv.y == my && (jb + 1) < n);
        rank += (sv.z > my) || (sv.z == my && (jb + 2) < n);
        rank += (sv.w > my) || (sv.w == my && (jb + 3) < n);
    }
    sel[(size_t)g * NPG + n] = (rank < k);
}

// ---------------- fused top-k2 + masked partial mean, 4 blocks/graph ------
__global__ __launch_bounds__(256) void topk2_mean(const float* __restrict__ sc2,
                                                  const int* __restrict__ sel1,
                                                  const float* __restrict__ feat,
                                                  float* __restrict__ partial) {
    __shared__ float s4[NPG];
    __shared__ int keep[128];
    __shared__ float vbuf[4][CC];
    const int b = blockIdx.x;    // 0..255
    const int g = b >> 2, p = b & 3;
    const int t = threadIdx.x;   // 0..255
    if (t < 128) {
        float4 v = *(const float4*)(sc2 + (size_t)g * NPG + t * 4);
        int4 mk = *(const int4*)(sel1 + (size_t)g * NPG + t * 4);
        v.x = mk.x ? v.x : -INFINITY;
        v.y = mk.y ? v.y : -INFINITY;
        v.z = mk.z ? v.z : -INFINITY;
        v.w = mk.w ? v.w : -INFINITY;
        *(float4*)(s4 + t * 4) = v;
    }
    __syncthreads();
    if (t < 128) {
        const int n = p * 128 + t;
        const float my = s4[n];
        int rank = 0;
#pragma unroll 16
        for (int j4 = 0; j4 < NPG / 4; ++j4) {
            const float4 sv = *(const float4*)(s4 + j4 * 4);
            const int jb = j4 * 4;
            rank += (sv.x > my) || (sv.x == my && (jb + 0) < n);
            rank += (sv.y > my) || (sv.y == my && (jb + 1) < n);
            rank += (sv.z > my) || (sv.z == my && (jb + 2) < n);
            rank += (sv.w > my) || (sv.w == my && (jb + 3) < n);
        }
        keep[t] = (rank < KP2) && sel1[(size_t)g * NPG + n];
    }
    __syncthreads();
    const int r = t >> 6, c4 = t & 63;
    float4 acc = make_float4(0.f, 0.f, 0.f, 0.f);
    const float4* f4 = (const float4*)(feat + ((size_t)g * NPG + p * 128) * CC);
    for (int j = r; j < 128; j += 4) {
        if (keep[j]) {
            float4 v = f4[j * 64 + c4];
            acc.x += v.x; acc.y += v.y; acc.z += v.z; acc.w += v.w;
        }
    }
    vbuf[r][c4 * 4 + 0] = acc.x;
    vbuf[r][c4 * 4 + 1] = acc.y;
    vbuf[r][c4 * 4 + 2] = acc.z;
    vbuf[r][c4 * 4 + 3] = acc.w;
    __syncthreads();
    partial[(size_t)(g * 4 + p) * CC + t] =
        vbuf[0][t] + vbuf[1][t] + vbuf[2][t] + vbuf[3][t];
}

// ---------------- folded head: relu(mean@Wc+bc)@c2w+c2b -> log_softmax ----
__global__ __launch_bounds__(256) void head_k(const float* __restrict__ partial,
                                              const float* __restrict__ Wc,
                                              const float* __restrict__ bc,
                                              const float* __restrict__ c2w,
                                              const float* __restrict__ c2b,
                                              float* __restrict__ out) {
    __shared__ float v0[CC];
    __shared__ float part[4][64];
    __shared__ float v2[64];
    const int g = blockIdx.x;
    const int i = threadIdx.x;
    float tsum = partial[(size_t)(g * 4 + 0) * CC + i] +
                 partial[(size_t)(g * 4 + 1) * CC + i] +
                 partial[(size_t)(g * 4 + 2) * CC + i] +
                 partial[(size_t)(g * 4 + 3) * CC + i];
    v0[i] = tsum * (1.0f / KP2);
    __syncthreads();
    {
        const int q = i >> 6, cth = i & 63;
        float p = 0.0f;
        for (int j = q * 64; j < q * 64 + 64; ++j)
            p = fmaf(v0[j], Wc[j * 64 + cth], p);
        part[q][cth] = p;
    }
    __syncthreads();
    if (i < 64) {
        float u = bc[i];
#pragma unroll
        for (int q = 0; q < 4; ++q) u += part[q][i];
        v2[i] = fmaxf(u, 0.0f);
    }
    __syncthreads();
    if (i < 2) {
        float o = c2b[i];
        for (int j = 0; j < 64; ++j) o = fmaf(v2[j], c2w[j * 2 + i], o);
        part[0][i] = o;
    }
    __syncthreads();
    if (i == 0) {
        float a = part[0][0], bq = part[0][1];
        float mx = fmaxf(a, bq);
        float lse = mx + logf(expf(a - mx) + expf(bq - mx));
        out[g * 2 + 0] = a - lse;
        out[g * 2 + 1] = bq - lse;
    }
}

// ---------------- launcher ----------------
extern "C" void kernel_launch(void* const* d_in, const int* in_sizes, int n_in,
                              void* d_out, int out_size, void* d_ws, size_t ws_size,
                              hipStream_t stream) {
    const float* x      = (const float*)d_in[0];
    const int*   ei     = (const int*)d_in[1];
    const int*   src    = ei;
    const int*   dst    = ei + EG;
    const float* W1     = (const float*)d_in[3];
    const float* a_src1 = (const float*)d_in[4];
    const float* a_dst1 = (const float*)d_in[5];
    const float* b1     = (const float*)d_in[6];
    const float* W2     = (const float*)d_in[7];
    const float* a_src2 = (const float*)d_in[8];
    const float* a_dst2 = (const float*)d_in[9];
    const float* b2     = (const float*)d_in[10];
    const float* p1_sw  = (const float*)d_in[11];
    const float* p1_sb  = (const float*)d_in[12];
    const float* p1_tw  = (const float*)d_in[13];
    const float* p1_tb  = (const float*)d_in[14];
    const float* p2_sw  = (const float*)d_in[15];
    const float* p2_sb  = (const float*)d_in[16];
    const float* p2_tw  = (const float*)d_in[17];
    const float* p2_tb  = (const float*)d_in[18];
    const float* c1w    = (const float*)d_in[19];
    const float* c1b    = (const float*)d_in[20];
    const float* c2w    = (const float*)d_in[21];
    const float* c2b    = (const float*)d_in[22];
    float* out = (float*)d_out;

    // workspace layout
    float* ws = (float*)d_ws;
    float* z = ws;                                      // NN*CC floats
    float* fregion = z + (size_t)NN * CC;               // NN*CC floats
    unsigned short* fhi = (unsigned short*)fregion;     //   phase 1: fhi/flo bf16
    unsigned short* flo = fhi + (size_t)NN * CC;
    float* featF = fregion;                             //   phase 2: fp32 feat (alias)
    float* wsp = fregion + (size_t)NN * CC;
    unsigned short* w1ph = (unsigned short*)wsp;        // 256*128 packed
    unsigned short* w1pl = w1ph + 256 * FIN;
    unsigned short* w2ph = w1pl + 256 * FIN;            // 256*256 packed
    unsigned short* w2pl = w2ph + 256 * CC;
    float* es  = (float*)(w2pl + 256 * CC);             // N*H
    float* ed  = es + NN * HH;
    int* rowp  = (int*)(ed + NN * HH);                  // N+1
    int* esrc  = rowp + NN + 1;                         // E
    float* sc1 = (float*)(esrc + EG);                   // N
    float* sc2 = sc1 + NN;                              // N
    int* sel1  = (int*)(sc2 + NN);                      // N
    float* w12 = (float*)(sel1 + NN);                   // C
    float* b12 = w12 + CC;                              // 1 (padded 64)
    float* T   = b12 + 64;                              // 256*64
    float* Wc  = T + CC * 64;                           // 256*64
    float* bc2 = Wc + CC * 64;                          // 64
    float* bcv = bc2 + 64;                              // 64
    float* partial = bcv + 64;                          // BG*4*CC

    // ---- prep + conversions + CSR build ----
    prep<<<66, 256, 0, stream>>>(p1_tw, p2_sw, p1_tb, p2_sb, w12, b12,
                                 p2_tw, c1w, p2_tb, T, bc2);
    conv_wpack<<<48, 256, 0, stream>>>(W1, W2, w1ph, w1pl, w2ph, w2pl);
    csr_build<<<BG, 1024, 0, stream>>>(src, dst, rowp, esrc);
    fold_W<<<65, 256, 0, stream>>>(p1_tw, T, p1_tb, bc2, c1b, Wc, bcv);

    // ---- GAT layer 1 (fp32 A split in-register) ----
    gemm_mfma_attn_f32<<<NN / 32, 256, 0, stream>>>(x, w1ph, w1pl, z, FIN,
                                                    a_src1, a_dst1, es, ed);
    gat_edge<<<NN / 4, 256, 0, stream>>>(z, rowp, esrc, es, ed, b1,
                                         nullptr, fhi, flo,
                                         nullptr, nullptr, nullptr, nullptr,
                                         nullptr, nullptr);

    // ---- GAT layer 2 ----
    gemm_mfma_attn<<<NN / 32, 256, 0, stream>>>(fhi, flo, w2ph, w2pl, z, CC,
                                                a_src2, a_dst2, es, ed);
    gat_edge<<<NN / 4, 256, 0, stream>>>(z, rowp, esrc, es, ed, b2,
                                         featF, nullptr, nullptr,
                                         p1_sw, p1_sb, w12, b12, sc1, sc2);

    // ---- pooling + folded head ----
    topk_ranks<<<BG * 4, 128, 0, stream>>>(sc1, sel1, KP1);
    topk2_mean<<<BG * 4, 256, 0, stream>>>(sc2, sel1, featF, partial);
    head_k<<<BG, 256, 0, stream>>>(partial, Wc, bcv, c2w, c2b, out);
}